// Round 1
// baseline (1529.855 us; speedup 1.0000x reference)
//
#include <hip/hip_runtime.h>
#include <hip/hip_bf16.h>

#define ED 1024
#define NH 16
#define HD 64
#define SEQ 2048

// ---------------------------------------------------------------------------
// GEMM: C[m][e] = sum_d A[m][d] * W[e][d] + bias[e]
// A: [M][ED] row-major fp32. W: [ED][ED] row-major [out][in] fp32.
// MODE 0: scatter output to [B, H, N, HD]  (for Q/K/V)
// MODE 1: plain [M][ED]                    (for final output)
// Tiling: 64x64 tile, BK=16, 256 threads, 4x4 per thread.
// ---------------------------------------------------------------------------
template <int MODE>
__global__ __launch_bounds__(256) void gemm_xwT(const float* __restrict__ A,
                                                const float* __restrict__ W,
                                                const float* __restrict__ bias,
                                                float* __restrict__ out) {
  __shared__ float As[16][68];  // As[k][m], pad 68 keeps 16B align + few conflicts
  __shared__ float Bs[16][68];  // Bs[k][n]

  const int tid = threadIdx.x;
  const int m0 = blockIdx.y * 64;
  const int n0 = blockIdx.x * 64;

  const int lm = tid >> 2;         // 0..63 row within tile for loading
  const int lk = (tid & 3) * 4;    // 0,4,8,12 k-offset for loading

  const int tm = (tid & 15) * 4;   // compute micro-tile row base
  const int tn = (tid >> 4) * 4;   // compute micro-tile col base

  float acc[4][4];
#pragma unroll
  for (int i = 0; i < 4; i++)
#pragma unroll
    for (int j = 0; j < 4; j++) acc[i][j] = 0.f;

  for (int k0 = 0; k0 < ED; k0 += 16) {
    const float4 av = *reinterpret_cast<const float4*>(&A[(size_t)(m0 + lm) * ED + k0 + lk]);
    const float4 bv = *reinterpret_cast<const float4*>(&W[(size_t)(n0 + lm) * ED + k0 + lk]);
    __syncthreads();  // previous iteration finished reading LDS
    As[lk + 0][lm] = av.x; As[lk + 1][lm] = av.y; As[lk + 2][lm] = av.z; As[lk + 3][lm] = av.w;
    Bs[lk + 0][lm] = bv.x; Bs[lk + 1][lm] = bv.y; Bs[lk + 2][lm] = bv.z; Bs[lk + 3][lm] = bv.w;
    __syncthreads();
#pragma unroll
    for (int k = 0; k < 16; k++) {
      const float4 a = *reinterpret_cast<const float4*>(&As[k][tm]);
      const float4 b = *reinterpret_cast<const float4*>(&Bs[k][tn]);
      acc[0][0] += a.x * b.x; acc[0][1] += a.x * b.y; acc[0][2] += a.x * b.z; acc[0][3] += a.x * b.w;
      acc[1][0] += a.y * b.x; acc[1][1] += a.y * b.y; acc[1][2] += a.y * b.z; acc[1][3] += a.y * b.w;
      acc[2][0] += a.z * b.x; acc[2][1] += a.z * b.y; acc[2][2] += a.z * b.z; acc[2][3] += a.z * b.w;
      acc[3][0] += a.w * b.x; acc[3][1] += a.w * b.y; acc[3][2] += a.w * b.z; acc[3][3] += a.w * b.w;
    }
  }

  const float b0 = bias[n0 + tn + 0];
  const float b1 = bias[n0 + tn + 1];
  const float b2 = bias[n0 + tn + 2];
  const float b3 = bias[n0 + tn + 3];

#pragma unroll
  for (int i = 0; i < 4; i++) {
    const int m = m0 + tm + i;
    float v0 = acc[i][0] + b0, v1 = acc[i][1] + b1, v2 = acc[i][2] + b2, v3 = acc[i][3] + b3;
    if (MODE == 0) {
      // scatter to [B, H, N, HD]: m -> (b, n), e -> (h, hd)
      const int b = m >> 11;        // /2048
      const int n = m & 2047;
#pragma unroll
      for (int j = 0; j < 4; j++) {
        const int e = n0 + tn + j;
        const int h = e >> 6;
        const int hd = e & 63;
        const float v = (j == 0) ? v0 : (j == 1) ? v1 : (j == 2) ? v2 : v3;
        out[(((size_t)(b * NH + h) * SEQ) + n) * HD + hd] = v;
      }
    } else {
      float* dst = &out[(size_t)m * ED + n0 + tn];
      dst[0] = v0; dst[1] = v1; dst[2] = v2; dst[3] = v3;
    }
  }
}

// ---------------------------------------------------------------------------
// Flash-style attention, fp32. One block = one (b,h) x 32 query rows.
// Q,K,V in [B*H, SEQ, HD]. CTX out in [B, N, ED] (= [B*N][ED], head-merged).
// 256 threads: thread t owns output row r = t>>3, dims d0 = (t&7)*8 .. +7.
// ---------------------------------------------------------------------------
__global__ __launch_bounds__(256) void attn_fp32(const float* __restrict__ Q,
                                                 const float* __restrict__ K,
                                                 const float* __restrict__ V,
                                                 float* __restrict__ CTX) {
  __shared__ float Qs[32][68];
  __shared__ float Ks[32][68];
  __shared__ float Vs[32][64];
  __shared__ float Ss[32][36];
  __shared__ float mrow[32], lrow[32], frow[32];

  const int tid = threadIdx.x;
  const int nqt = SEQ / 32;            // 64 q-tiles per head
  const int qt = blockIdx.x % nqt;
  const int bh = blockIdx.x / nqt;     // 0..B*NH-1

  const float* Qh = Q + (size_t)bh * SEQ * HD;
  const float* Kh = K + (size_t)bh * SEQ * HD;
  const float* Vh = V + (size_t)bh * SEQ * HD;

  const int lr = tid >> 3;        // 0..31 row
  const int lc = (tid & 7) * 8;   // 0..56 col base (8 floats per thread)

  // load + pre-scale Q tile (fold 1/sqrt(HD))
  {
    const float s = 0.125f;
    const float4 q0 = *reinterpret_cast<const float4*>(&Qh[(size_t)(qt * 32 + lr) * HD + lc]);
    const float4 q1 = *reinterpret_cast<const float4*>(&Qh[(size_t)(qt * 32 + lr) * HD + lc + 4]);
    Qs[lr][lc + 0] = q0.x * s; Qs[lr][lc + 1] = q0.y * s; Qs[lr][lc + 2] = q0.z * s; Qs[lr][lc + 3] = q0.w * s;
    Qs[lr][lc + 4] = q1.x * s; Qs[lr][lc + 5] = q1.y * s; Qs[lr][lc + 6] = q1.z * s; Qs[lr][lc + 7] = q1.w * s;
  }
  if (tid < 32) { mrow[tid] = -1e30f; lrow[tid] = 0.f; }

  const int r = tid >> 3;          // output row owned by this thread
  const int d0 = (tid & 7) * 8;    // output dim base
  float o[8];
#pragma unroll
  for (int j = 0; j < 8; j++) o[j] = 0.f;

  const int r2 = tid >> 3;         // score row
  const int c2 = (tid & 7) * 4;    // score col base (4 scores per thread)

  for (int kt = 0; kt < SEQ / 32; ++kt) {
    const float4 k0v = *reinterpret_cast<const float4*>(&Kh[(size_t)(kt * 32 + lr) * HD + lc]);
    const float4 k1v = *reinterpret_cast<const float4*>(&Kh[(size_t)(kt * 32 + lr) * HD + lc + 4]);
    const float4 v0v = *reinterpret_cast<const float4*>(&Vh[(size_t)(kt * 32 + lr) * HD + lc]);
    const float4 v1v = *reinterpret_cast<const float4*>(&Vh[(size_t)(kt * 32 + lr) * HD + lc + 4]);
    __syncthreads();  // (A) prev iter done reading Ks/Vs/Ss; Qs published (iter 0)
    Ks[lr][lc + 0] = k0v.x; Ks[lr][lc + 1] = k0v.y; Ks[lr][lc + 2] = k0v.z; Ks[lr][lc + 3] = k0v.w;
    Ks[lr][lc + 4] = k1v.x; Ks[lr][lc + 5] = k1v.y; Ks[lr][lc + 6] = k1v.z; Ks[lr][lc + 7] = k1v.w;
    Vs[lr][lc + 0] = v0v.x; Vs[lr][lc + 1] = v0v.y; Vs[lr][lc + 2] = v0v.z; Vs[lr][lc + 3] = v0v.w;
    Vs[lr][lc + 4] = v1v.x; Vs[lr][lc + 5] = v1v.y; Vs[lr][lc + 6] = v1v.z; Vs[lr][lc + 7] = v1v.w;
    __syncthreads();  // (B) K/V tiles visible

    // scores: S[r2][c2..c2+3] = Qs[r2][:] . Ks[c2+cc][:]
    float sacc[4] = {0.f, 0.f, 0.f, 0.f};
#pragma unroll
    for (int k4 = 0; k4 < 16; k4++) {
      const float4 q = *reinterpret_cast<const float4*>(&Qs[r2][k4 * 4]);
#pragma unroll
      for (int cc = 0; cc < 4; cc++) {
        const float4 kv = *reinterpret_cast<const float4*>(&Ks[c2 + cc][k4 * 4]);
        sacc[cc] += q.x * kv.x + q.y * kv.y + q.z * kv.z + q.w * kv.w;
      }
    }
#pragma unroll
    for (int cc = 0; cc < 4; cc++) Ss[r2][c2 + cc] = sacc[cc];
    __syncthreads();  // (C) scores visible

    // online softmax update (serial per row; lanes 0..31)
    if (tid < 32) {
      const int rr = tid;
      float tmax = -1e30f;
#pragma unroll
      for (int c = 0; c < 32; c++) tmax = fmaxf(tmax, Ss[rr][c]);
      const float mold = mrow[rr];
      const float nm = fmaxf(mold, tmax);
      const float f = __expf(mold - nm);
      float sum = 0.f;
#pragma unroll
      for (int c = 0; c < 32; c++) {
        const float p = __expf(Ss[rr][c] - nm);
        Ss[rr][c] = p;
        sum += p;
      }
      lrow[rr] = lrow[rr] * f + sum;
      mrow[rr] = nm;
      frow[rr] = f;
    }
    __syncthreads();  // (D) probabilities + rescale factors visible

    // O = O*f + P . V
    const float f = frow[r];
#pragma unroll
    for (int j = 0; j < 8; j++) o[j] *= f;
#pragma unroll
    for (int c = 0; c < 32; c++) {
      const float p = Ss[r][c];
      const float4 v0 = *reinterpret_cast<const float4*>(&Vs[c][d0]);
      const float4 v1 = *reinterpret_cast<const float4*>(&Vs[c][d0 + 4]);
      o[0] += p * v0.x; o[1] += p * v0.y; o[2] += p * v0.z; o[3] += p * v0.w;
      o[4] += p * v1.x; o[5] += p * v1.y; o[6] += p * v1.z; o[7] += p * v1.w;
    }
  }

  // epilogue: normalize + write ctx in [B, N, ED] with heads merged
  const float inv = 1.0f / lrow[r];
  const int b = bh / NH;
  const int h = bh % NH;
  const int n = qt * 32 + r;
  float* dst = &CTX[((size_t)(b * SEQ + n)) * ED + h * HD + d0];
  float4 w0, w1;
  w0.x = o[0] * inv; w0.y = o[1] * inv; w0.z = o[2] * inv; w0.w = o[3] * inv;
  w1.x = o[4] * inv; w1.y = o[5] * inv; w1.z = o[6] * inv; w1.w = o[7] * inv;
  *reinterpret_cast<float4*>(&dst[0]) = w0;
  *reinterpret_cast<float4*>(&dst[4]) = w1;
}

// ---------------------------------------------------------------------------
extern "C" void kernel_launch(void* const* d_in, const int* in_sizes, int n_in,
                              void* d_out, int out_size, void* d_ws, size_t ws_size,
                              hipStream_t stream) {
  const float* x  = (const float*)d_in[0];
  const float* wq = (const float*)d_in[1];
  const float* bq = (const float*)d_in[2];
  const float* wk = (const float*)d_in[3];
  const float* bk = (const float*)d_in[4];
  const float* wv = (const float*)d_in[5];
  const float* bv = (const float*)d_in[6];
  const float* wo = (const float*)d_in[7];
  const float* bo = (const float*)d_in[8];
  float* out = (float*)d_out;

  const int BN = in_sizes[0] / ED;  // B*N = 4096
  const int B  = BN / SEQ;          // 2

  // workspace: Q | K | V | CTX, each BN*ED fp32 (16 MB) -> 64 MB total
  float* Qw  = (float*)d_ws;
  float* Kw  = Qw + (size_t)BN * ED;
  float* Vw  = Kw + (size_t)BN * ED;
  float* CTX = Vw + (size_t)BN * ED;

  const dim3 blk(256);
  const dim3 gg(ED / 64, BN / 64);  // (16, 64)

  gemm_xwT<0><<<gg, blk, 0, stream>>>(x, wq, bq, Qw);
  gemm_xwT<0><<<gg, blk, 0, stream>>>(x, wk, bk, Kw);
  gemm_xwT<0><<<gg, blk, 0, stream>>>(x, wv, bv, Vw);

  const dim3 ga(B * NH * (SEQ / 32));  // 2048 blocks
  attn_fp32<<<ga, blk, 0, stream>>>(Qw, Kw, Vw, CTX);

  gemm_xwT<1><<<gg, blk, 0, stream>>>(CTX, wo, bo, out);
}

// Round 2
// 332.408 us; speedup vs baseline: 4.6023x; 4.6023x over previous
//
#include <hip/hip_runtime.h>
#include <hip/hip_bf16.h>

#define ED 1024
#define NH 16
#define HD 64
#define SEQ 2048

typedef float f32x4 __attribute__((ext_vector_type(4)));
typedef short s16x8 __attribute__((ext_vector_type(8)));
typedef __attribute__((address_space(1))) const unsigned int GBuf;
typedef __attribute__((address_space(3))) unsigned int LBuf;

union BF8 { s16x8 v; __hip_bfloat16 h[8]; };

// ---------------------------------------------------------------------------
// fp32 -> bf16 conversion (vectorized, grid-stride)
// ---------------------------------------------------------------------------
__device__ inline void cvt_one(const float* __restrict__ s, __hip_bfloat16* __restrict__ d,
                               int n, int t, int stride) {
  const int n8 = n >> 3;
  for (int i = t; i < n8; i += stride) {
    const float4 u = ((const float4*)s)[2 * i];
    const float4 v = ((const float4*)s)[2 * i + 1];
    BF8 o;
    o.h[0] = __float2bfloat16(u.x); o.h[1] = __float2bfloat16(u.y);
    o.h[2] = __float2bfloat16(u.z); o.h[3] = __float2bfloat16(u.w);
    o.h[4] = __float2bfloat16(v.x); o.h[5] = __float2bfloat16(v.y);
    o.h[6] = __float2bfloat16(v.z); o.h[7] = __float2bfloat16(v.w);
    ((s16x8*)d)[i] = o.v;
  }
}

__global__ __launch_bounds__(256) void cvt5(const float* s0, const float* s1, const float* s2,
                                            const float* s3, const float* s4,
                                            __hip_bfloat16* d0, __hip_bfloat16* d1,
                                            __hip_bfloat16* d2, __hip_bfloat16* d3,
                                            __hip_bfloat16* d4,
                                            int n0, int n1, int n2, int n3, int n4) {
  const int stride = gridDim.x * blockDim.x;
  const int t = blockIdx.x * blockDim.x + threadIdx.x;
  cvt_one(s0, d0, n0, t, stride);
  cvt_one(s1, d1, n1, t, stride);
  cvt_one(s2, d2, n2, t, stride);
  cvt_one(s3, d3, n3, t, stride);
  cvt_one(s4, d4, n4, t, stride);
}

// ---------------------------------------------------------------------------
// bf16 MFMA GEMM: C[m][e] = sum_k A[m][k] * W[e][k] + bias[e]
// A: [M][1024] bf16, W: [1024][1024] bf16 ([out][in] => both K-contiguous).
// 128x128 tile, BK=64, 256 thr = 4 waves each computing a 64x64 quadrant.
// global_load_lds width-16 staging, linear LDS (T2 null at 2-phase).
// MODE 0: out bf16 scattered to [B*NH][SEQ][HD], value (acc+bias)*scale
// MODE 1: out fp32 [M][1024], value acc+bias
// ---------------------------------------------------------------------------
template <int MODE>
__global__ __launch_bounds__(256) void gemm_bf16(const __hip_bfloat16* __restrict__ A,
                                                 const __hip_bfloat16* __restrict__ W,
                                                 const float* __restrict__ bias,
                                                 void* __restrict__ outp, float scale) {
  __shared__ __hip_bfloat16 As[128 * 64];
  __shared__ __hip_bfloat16 Bs[128 * 64];

  const int tid = threadIdx.x;
  const int wave = tid >> 6, lane = tid & 63;
  const int ln15 = lane & 15, lg = lane >> 4;
  const int m0 = blockIdx.y * 128, n0 = blockIdx.x * 128;
  const int wr = (wave >> 1) * 64, wc = (wave & 1) * 64;

  f32x4 acc[4][4];
#pragma unroll
  for (int i = 0; i < 4; i++)
#pragma unroll
    for (int j = 0; j < 4; j++) acc[i][j] = (f32x4){0.f, 0.f, 0.f, 0.f};

  const int srow = tid >> 3;           // 0..31 row per staging call
  const int sk = (tid & 7) * 8;        // k offset (8 bf16 = 16 B)

  for (int k0 = 0; k0 < ED; k0 += 64) {
    __syncthreads();  // previous compute done reading LDS
#pragma unroll
    for (int c = 0; c < 4; c++) {
      const int r = c * 32 + srow;
      __builtin_amdgcn_global_load_lds((GBuf*)(A + (size_t)(m0 + r) * ED + k0 + sk),
                                       (LBuf*)((char*)As + c * 4096 + tid * 16), 16, 0, 0);
    }
#pragma unroll
    for (int c = 0; c < 4; c++) {
      const int r = c * 32 + srow;
      __builtin_amdgcn_global_load_lds((GBuf*)(W + (size_t)(n0 + r) * ED + k0 + sk),
                                       (LBuf*)((char*)Bs + c * 4096 + tid * 16), 16, 0, 0);
    }
    __syncthreads();  // drains vmcnt (barrier semantics) -> tiles visible
#pragma unroll
    for (int kb = 0; kb < 2; kb++) {
      const int kof = kb * 32 + lg * 8;
      s16x8 a[4], b[4];
#pragma unroll
      for (int i = 0; i < 4; i++)
        a[i] = *(const s16x8*)&As[(wr + i * 16 + ln15) * 64 + kof];
#pragma unroll
      for (int j = 0; j < 4; j++)
        b[j] = *(const s16x8*)&Bs[(wc + j * 16 + ln15) * 64 + kof];
#pragma unroll
      for (int i = 0; i < 4; i++)
#pragma unroll
        for (int j = 0; j < 4; j++)
          acc[i][j] = __builtin_amdgcn_mfma_f32_16x16x32_bf16(a[i], b[j], acc[i][j], 0, 0, 0);
    }
  }

  // epilogue: C row = (lg*4 + reg), col = ln15 within each 16x16 block
#pragma unroll
  for (int j = 0; j < 4; j++) {
    const int e = n0 + wc + j * 16 + ln15;
    const float bv = bias[e];
#pragma unroll
    for (int i = 0; i < 4; i++) {
#pragma unroll
      for (int r = 0; r < 4; r++) {
        const int m = m0 + wr + i * 16 + lg * 4 + r;
        const float v = acc[i][j][r] + bv;
        if (MODE == 0) {
          __hip_bfloat16* out = (__hip_bfloat16*)outp;
          const int b = m >> 11, n = m & 2047;     // m -> (batch, seq)
          const int h = e >> 6, hd = e & 63;       // e -> (head, hd)
          out[(((size_t)(b * NH + h)) * SEQ + n) * HD + hd] = __float2bfloat16(v * scale);
        } else {
          ((float*)outp)[(size_t)m * ED + e] = v;
        }
      }
    }
  }
}

// ---------------------------------------------------------------------------
// Flash attention, bf16 MFMA, fp32 online softmax in registers.
// Q pre-scaled by 1/sqrt(HD). Block = 256 thr (4 waves); wave owns 16 q-rows.
// KV tile = 64. LDS rows padded to 72 elems (144 B): conflict-free b128 reads.
// C-layout (16x16x32): col = lane&15, row = (lane>>4)*4 + reg.
// ---------------------------------------------------------------------------
__global__ __launch_bounds__(256) void attn_bf16(const __hip_bfloat16* __restrict__ Q,
                                                 const __hip_bfloat16* __restrict__ K,
                                                 const __hip_bfloat16* __restrict__ V,
                                                 __hip_bfloat16* __restrict__ CTX) {
  __shared__ __hip_bfloat16 Ks[64 * 72];      // K rows, padded
  __shared__ __hip_bfloat16 Vt[64 * 72];      // V transposed: Vt[d][kv]
  __shared__ __hip_bfloat16 Ps[4][16 * 72];   // per-wave P tile

  const int tid = threadIdx.x;
  const int wave = tid >> 6, lane = tid & 63;
  const int ln15 = lane & 15, lg = lane >> 4;

  const int qt = blockIdx.x & 31;    // 32 q-tiles of 64
  const int bh = blockIdx.x >> 5;    // 0..31

  const __hip_bfloat16* Qh = Q + (size_t)bh * SEQ * HD;
  const __hip_bfloat16* Kh = K + (size_t)bh * SEQ * HD;
  const __hip_bfloat16* Vh = V + (size_t)bh * SEQ * HD;

  // Q fragments live in registers for the whole kernel (16 rows per wave)
  s16x8 aq[2];
  {
    const int qrow = qt * 64 + wave * 16 + ln15;
#pragma unroll
    for (int kb = 0; kb < 2; kb++)
      aq[kb] = *(const s16x8*)&Qh[(size_t)qrow * HD + kb * 32 + lg * 8];
  }

  f32x4 acc_o[4];
#pragma unroll
  for (int d = 0; d < 4; d++) acc_o[d] = (f32x4){0.f, 0.f, 0.f, 0.f};
  float mrow[4], lrow[4];
#pragma unroll
  for (int r = 0; r < 4; r++) { mrow[r] = -1e30f; lrow[r] = 0.f; }

  const int skv = tid >> 2;         // staging row 0..63
  const int sd = (tid & 3) * 16;    // staging col base

  for (int kt = 0; kt < SEQ / 64; kt++) {
    // issue global loads before the barrier (hide latency under prev PV)
    const size_t gbase = (size_t)(kt * 64 + skv) * HD + sd;
    const s16x8 k0v = *(const s16x8*)&Kh[gbase];
    const s16x8 k1v = *(const s16x8*)&Kh[gbase + 8];
    const s16x8 v0v = *(const s16x8*)&Vh[gbase];
    const s16x8 v1v = *(const s16x8*)&Vh[gbase + 8];
    __syncthreads();  // prev iter done reading Ks/Vt/Ps
    *(s16x8*)&Ks[skv * 72 + sd] = k0v;
    *(s16x8*)&Ks[skv * 72 + sd + 8] = k1v;
    {
      BF8 a, b;
      a.v = v0v; b.v = v1v;
#pragma unroll
      for (int e = 0; e < 8; e++) {
        Vt[(sd + e) * 72 + skv] = a.h[e];
        Vt[(sd + 8 + e) * 72 + skv] = b.h[e];
      }
    }
    __syncthreads();  // tiles visible

    // S = Q * K^T   (A=Q rows q, B=K^T: col=kv reads K[kv][d] contiguous)
    f32x4 accs[4];
#pragma unroll
    for (int cb = 0; cb < 4; cb++) accs[cb] = (f32x4){0.f, 0.f, 0.f, 0.f};
#pragma unroll
    for (int cb = 0; cb < 4; cb++) {
#pragma unroll
      for (int kb = 0; kb < 2; kb++) {
        const s16x8 bk = *(const s16x8*)&Ks[(cb * 16 + ln15) * 72 + kb * 32 + lg * 8];
        accs[cb] = __builtin_amdgcn_mfma_f32_16x16x32_bf16(aq[kb], bk, accs[cb], 0, 0, 0);
      }
    }

    // online softmax: rows owned = lg*4 + r; reduce over cols = shfl over low 4 bits
    float tmax[4];
#pragma unroll
    for (int r = 0; r < 4; r++)
      tmax[r] = fmaxf(fmaxf(accs[0][r], accs[1][r]), fmaxf(accs[2][r], accs[3][r]));
#pragma unroll
    for (int mk = 1; mk <= 8; mk <<= 1)
#pragma unroll
      for (int r = 0; r < 4; r++) tmax[r] = fmaxf(tmax[r], __shfl_xor(tmax[r], mk));

    float f[4], sum[4], p[4][4];
#pragma unroll
    for (int r = 0; r < 4; r++) {
      const float mnew = fmaxf(mrow[r], tmax[r]);
      f[r] = __expf(mrow[r] - mnew);
      mrow[r] = mnew;
      sum[r] = 0.f;
#pragma unroll
      for (int cb = 0; cb < 4; cb++) {
        p[cb][r] = __expf(accs[cb][r] - mnew);
        sum[r] += p[cb][r];
      }
    }
#pragma unroll
    for (int mk = 1; mk <= 8; mk <<= 1)
#pragma unroll
      for (int r = 0; r < 4; r++) sum[r] += __shfl_xor(sum[r], mk);
#pragma unroll
    for (int r = 0; r < 4; r++) lrow[r] = lrow[r] * f[r] + sum[r];

    // P -> LDS (bf16), per-wave region
#pragma unroll
    for (int cb = 0; cb < 4; cb++)
#pragma unroll
      for (int r = 0; r < 4; r++)
        Ps[wave][(lg * 4 + r) * 72 + cb * 16 + ln15] = __float2bfloat16(p[cb][r]);

    // rescale O by exp(m_old - m_new)
#pragma unroll
    for (int d = 0; d < 4; d++)
#pragma unroll
      for (int r = 0; r < 4; r++) acc_o[d][r] *= f[r];

    __syncthreads();  // P visible

    // O += P * V   (A=P rows q, K-dim kv; B=V: col=d reads Vt[d][kv] contiguous)
#pragma unroll
    for (int kb = 0; kb < 2; kb++) {
      const s16x8 ap = *(const s16x8*)&Ps[wave][ln15 * 72 + kb * 32 + lg * 8];
#pragma unroll
      for (int d = 0; d < 4; d++) {
        const s16x8 bv = *(const s16x8*)&Vt[(d * 16 + ln15) * 72 + kb * 32 + lg * 8];
        acc_o[d] = __builtin_amdgcn_mfma_f32_16x16x32_bf16(ap, bv, acc_o[d], 0, 0, 0);
      }
    }
  }

  // epilogue: normalize, write ctx bf16 into [B, N, ED] (heads merged)
  const int b = bh / NH, h = bh % NH;
#pragma unroll
  for (int r = 0; r < 4; r++) {
    const float inv = 1.0f / lrow[r];
    const int n = qt * 64 + wave * 16 + lg * 4 + r;
#pragma unroll
    for (int d = 0; d < 4; d++)
      CTX[((size_t)(b * SEQ + n)) * ED + h * HD + d * 16 + ln15] =
          __float2bfloat16(acc_o[d][r] * inv);
  }
}

// ---------------------------------------------------------------------------
extern "C" void kernel_launch(void* const* d_in, const int* in_sizes, int n_in,
                              void* d_out, int out_size, void* d_ws, size_t ws_size,
                              hipStream_t stream) {
  const float* x = (const float*)d_in[0];
  const float* wq = (const float*)d_in[1];
  const float* bq = (const float*)d_in[2];
  const float* wk = (const float*)d_in[3];
  const float* bk = (const float*)d_in[4];
  const float* wv = (const float*)d_in[5];
  const float* bv = (const float*)d_in[6];
  const float* wo = (const float*)d_in[7];
  const float* bo = (const float*)d_in[8];
  float* out = (float*)d_out;

  const int BN = in_sizes[0] / ED;  // 4096

  // workspace (bf16): xbf | wq | wk | wv | wo | Q | K | V | CTX  (~48 MB)
  char* w = (char*)d_ws;
  __hip_bfloat16* xbf = (__hip_bfloat16*)(w);
  __hip_bfloat16* wqb = (__hip_bfloat16*)(w + (8 << 20));
  __hip_bfloat16* wkb = (__hip_bfloat16*)(w + (10 << 20));
  __hip_bfloat16* wvb = (__hip_bfloat16*)(w + (12 << 20));
  __hip_bfloat16* wob = (__hip_bfloat16*)(w + (14 << 20));
  __hip_bfloat16* Qb = (__hip_bfloat16*)(w + (16 << 20));
  __hip_bfloat16* Kb = (__hip_bfloat16*)(w + (24 << 20));
  __hip_bfloat16* Vb = (__hip_bfloat16*)(w + (32 << 20));
  __hip_bfloat16* CTXb = (__hip_bfloat16*)(w + (40 << 20));

  cvt5<<<1024, 256, 0, stream>>>(x, wq, wk, wv, wo, xbf, wqb, wkb, wvb, wob,
                                 BN * ED, ED * ED, ED * ED, ED * ED, ED * ED);

  const dim3 blk(256);
  const dim3 gg(ED / 128, BN / 128);  // (8, 32)
  gemm_bf16<0><<<gg, blk, 0, stream>>>(xbf, wqb, bq, Qb, 0.125f);   // Q pre-scaled
  gemm_bf16<0><<<gg, blk, 0, stream>>>(xbf, wkb, bk, Kb, 1.0f);
  gemm_bf16<0><<<gg, blk, 0, stream>>>(xbf, wvb, bv, Vb, 1.0f);

  attn_bf16<<<dim3(32 * 32), blk, 0, stream>>>(Qb, Kb, Vb, CTXb);

  gemm_bf16<1><<<gg, blk, 0, stream>>>(CTXb, wob, bo, out, 1.0f);
}

// Round 4
// 263.568 us; speedup vs baseline: 5.8044x; 1.2612x over previous
//
#include <hip/hip_runtime.h>
#include <hip/hip_bf16.h>

#define ED 1024
#define NH 16
#define HD 64
#define SEQ 2048

typedef float f32x4 __attribute__((ext_vector_type(4)));
typedef short s16x8 __attribute__((ext_vector_type(8)));
typedef short s16x4 __attribute__((ext_vector_type(4)));
typedef __attribute__((address_space(1))) const unsigned int GBuf;
typedef __attribute__((address_space(3))) unsigned int LBuf;

#define QSC 0.18033688011112042f  // 0.125 * log2(e): fold softmax scale + exp2 base

union BF8 { s16x8 v; __hip_bfloat16 h[8]; };

// ---------------------------------------------------------------------------
// fp32 -> bf16 conversion (vectorized, grid-stride)
// ---------------------------------------------------------------------------
__device__ inline void cvt_one(const float* __restrict__ s, __hip_bfloat16* __restrict__ d,
                               int n, int t, int stride) {
  const int n8 = n >> 3;
  for (int i = t; i < n8; i += stride) {
    const float4 u = ((const float4*)s)[2 * i];
    const float4 v = ((const float4*)s)[2 * i + 1];
    BF8 o;
    o.h[0] = __float2bfloat16(u.x); o.h[1] = __float2bfloat16(u.y);
    o.h[2] = __float2bfloat16(u.z); o.h[3] = __float2bfloat16(u.w);
    o.h[4] = __float2bfloat16(v.x); o.h[5] = __float2bfloat16(v.y);
    o.h[6] = __float2bfloat16(v.z); o.h[7] = __float2bfloat16(v.w);
    ((s16x8*)d)[i] = o.v;
  }
}

__global__ __launch_bounds__(256) void cvt5(const float* s0, const float* s1, const float* s2,
                                            const float* s3, const float* s4,
                                            __hip_bfloat16* d0, __hip_bfloat16* d1,
                                            __hip_bfloat16* d2, __hip_bfloat16* d3,
                                            __hip_bfloat16* d4,
                                            int n0, int n1, int n2, int n3, int n4) {
  const int stride = gridDim.x * blockDim.x;
  const int t = blockIdx.x * blockDim.x + threadIdx.x;
  cvt_one(s0, d0, n0, t, stride);
  cvt_one(s1, d1, n1, t, stride);
  cvt_one(s2, d2, n2, t, stride);
  cvt_one(s3, d3, n3, t, stride);
  cvt_one(s4, d4, n4, t, stride);
}

// ---------------------------------------------------------------------------
// Fused QKV GEMM. z = blockIdx.z selects {Q,K,V}.
// C[m][e] = sum_k x[m][k] * W[e][k] + bias[e]
// z<2 : out bf16 [B*NH][SEQ][HD], value (acc+bias)*scale  (Q: scale=QSC)
// z==2: out bf16 V^T [B*NH][HD][SEQ], packed 4-contiguous stores
// 128x128 tile, BK=64, 4 waves x 64x64 quadrant, global_load_lds staging.
// ---------------------------------------------------------------------------
__global__ __launch_bounds__(256) void gemm_qkv(const __hip_bfloat16* __restrict__ A,
                                                const __hip_bfloat16* __restrict__ wq,
                                                const float* __restrict__ bq,
                                                const __hip_bfloat16* __restrict__ wk,
                                                const float* __restrict__ bk,
                                                const __hip_bfloat16* __restrict__ wv,
                                                const float* __restrict__ bv,
                                                __hip_bfloat16* __restrict__ Qo,
                                                __hip_bfloat16* __restrict__ Ko,
                                                __hip_bfloat16* __restrict__ Vo) {
  __shared__ __hip_bfloat16 As[128 * 64];
  __shared__ __hip_bfloat16 Bs[128 * 64];

  const int z = blockIdx.z;
  const __hip_bfloat16* W = (z == 0) ? wq : (z == 1) ? wk : wv;
  const float* bias = (z == 0) ? bq : (z == 1) ? bk : bv;

  const int tid = threadIdx.x;
  const int wave = tid >> 6, lane = tid & 63;
  const int ln15 = lane & 15, lg = lane >> 4;
  const int m0 = blockIdx.y * 128, n0 = blockIdx.x * 128;
  const int wr = (wave >> 1) * 64, wc = (wave & 1) * 64;

  f32x4 acc[4][4];
#pragma unroll
  for (int i = 0; i < 4; i++)
#pragma unroll
    for (int j = 0; j < 4; j++) acc[i][j] = (f32x4){0.f, 0.f, 0.f, 0.f};

  const int srow = tid >> 3;
  const int sk = (tid & 7) * 8;

  for (int k0 = 0; k0 < ED; k0 += 64) {
    __syncthreads();
#pragma unroll
    for (int c = 0; c < 4; c++) {
      const int r = c * 32 + srow;
      __builtin_amdgcn_global_load_lds((GBuf*)(A + (size_t)(m0 + r) * ED + k0 + sk),
                                       (LBuf*)((char*)As + c * 4096 + tid * 16), 16, 0, 0);
    }
#pragma unroll
    for (int c = 0; c < 4; c++) {
      const int r = c * 32 + srow;
      __builtin_amdgcn_global_load_lds((GBuf*)(W + (size_t)(n0 + r) * ED + k0 + sk),
                                       (LBuf*)((char*)Bs + c * 4096 + tid * 16), 16, 0, 0);
    }
    __syncthreads();
#pragma unroll
    for (int kb = 0; kb < 2; kb++) {
      const int kof = kb * 32 + lg * 8;
      s16x8 a[4], b[4];
#pragma unroll
      for (int i = 0; i < 4; i++)
        a[i] = *(const s16x8*)&As[(wr + i * 16 + ln15) * 64 + kof];
#pragma unroll
      for (int j = 0; j < 4; j++)
        b[j] = *(const s16x8*)&Bs[(wc + j * 16 + ln15) * 64 + kof];
#pragma unroll
      for (int i = 0; i < 4; i++)
#pragma unroll
        for (int j = 0; j < 4; j++)
          acc[i][j] = __builtin_amdgcn_mfma_f32_16x16x32_bf16(a[i], b[j], acc[i][j], 0, 0, 0);
    }
  }

  const float scale = (z == 0) ? QSC : 1.0f;
  if (z < 2) {
    __hip_bfloat16* out = (z == 0) ? Qo : Ko;
#pragma unroll
    for (int j = 0; j < 4; j++) {
      const int e = n0 + wc + j * 16 + ln15;
      const float bvv = bias[e];
      const int h = e >> 6, hd = e & 63;
#pragma unroll
      for (int i = 0; i < 4; i++) {
#pragma unroll
        for (int r = 0; r < 4; r++) {
          const int m = m0 + wr + i * 16 + lg * 4 + r;
          const int b = m >> 11, n = m & 2047;
          out[(((size_t)(b * NH + h)) * SEQ + n) * HD + hd] =
              __float2bfloat16((acc[i][j][r] + bvv) * scale);
        }
      }
    }
  } else {
    // V^T scatter: [B*NH][HD][SEQ]; r -> n contiguous -> 4-elem packed stores
#pragma unroll
    for (int j = 0; j < 4; j++) {
      const int e = n0 + wc + j * 16 + ln15;
      const float bvv = bias[e];
      const int h = e >> 6, hd = e & 63;
#pragma unroll
      for (int i = 0; i < 4; i++) {
        const int m = m0 + wr + i * 16 + lg * 4;
        const int b = m >> 11, n = m & 2047;
        union { s16x4 v; __hip_bfloat16 hh[4]; } pk;
#pragma unroll
        for (int r = 0; r < 4; r++) pk.hh[r] = __float2bfloat16(acc[i][j][r] + bvv);
        *(s16x4*)&Vo[(((size_t)(b * NH + h)) * HD + hd) * SEQ + n] = pk.v;
      }
    }
  }
}

// ---------------------------------------------------------------------------
// Output GEMM: out fp32 [M][ED] = CTX @ Wo^T + bo
// ---------------------------------------------------------------------------
__global__ __launch_bounds__(256) void gemm_out(const __hip_bfloat16* __restrict__ A,
                                                const __hip_bfloat16* __restrict__ W,
                                                const float* __restrict__ bias,
                                                float* __restrict__ out) {
  __shared__ __hip_bfloat16 As[128 * 64];
  __shared__ __hip_bfloat16 Bs[128 * 64];

  const int tid = threadIdx.x;
  const int wave = tid >> 6, lane = tid & 63;
  const int ln15 = lane & 15, lg = lane >> 4;
  const int m0 = blockIdx.y * 128, n0 = blockIdx.x * 128;
  const int wr = (wave >> 1) * 64, wc = (wave & 1) * 64;

  f32x4 acc[4][4];
#pragma unroll
  for (int i = 0; i < 4; i++)
#pragma unroll
    for (int j = 0; j < 4; j++) acc[i][j] = (f32x4){0.f, 0.f, 0.f, 0.f};

  const int srow = tid >> 3;
  const int sk = (tid & 7) * 8;

  for (int k0 = 0; k0 < ED; k0 += 64) {
    __syncthreads();
#pragma unroll
    for (int c = 0; c < 4; c++) {
      const int r = c * 32 + srow;
      __builtin_amdgcn_global_load_lds((GBuf*)(A + (size_t)(m0 + r) * ED + k0 + sk),
                                       (LBuf*)((char*)As + c * 4096 + tid * 16), 16, 0, 0);
    }
#pragma unroll
    for (int c = 0; c < 4; c++) {
      const int r = c * 32 + srow;
      __builtin_amdgcn_global_load_lds((GBuf*)(W + (size_t)(n0 + r) * ED + k0 + sk),
                                       (LBuf*)((char*)Bs + c * 4096 + tid * 16), 16, 0, 0);
    }
    __syncthreads();
#pragma unroll
    for (int kb = 0; kb < 2; kb++) {
      const int kof = kb * 32 + lg * 8;
      s16x8 a[4], b[4];
#pragma unroll
      for (int i = 0; i < 4; i++)
        a[i] = *(const s16x8*)&As[(wr + i * 16 + ln15) * 64 + kof];
#pragma unroll
      for (int j = 0; j < 4; j++)
        b[j] = *(const s16x8*)&Bs[(wc + j * 16 + ln15) * 64 + kof];
#pragma unroll
      for (int i = 0; i < 4; i++)
#pragma unroll
        for (int j = 0; j < 4; j++)
          acc[i][j] = __builtin_amdgcn_mfma_f32_16x16x32_bf16(a[i], b[j], acc[i][j], 0, 0, 0);
    }
  }

#pragma unroll
  for (int j = 0; j < 4; j++) {
    const int e = n0 + wc + j * 16 + ln15;
    const float bvv = bias[e];
#pragma unroll
    for (int i = 0; i < 4; i++)
#pragma unroll
      for (int r = 0; r < 4; r++) {
        const int m = m0 + wr + i * 16 + lg * 4 + r;
        out[(size_t)m * ED + e] = acc[i][j][r] + bvv;
      }
  }
}

// ---------------------------------------------------------------------------
// Flash attention, swapped-operand S^T scheme.
// Q,K: [B*NH][SEQ][HD] bf16 (Q pre-scaled by QSC); VT: [B*NH][HD][SEQ] bf16.
// Block = 4 waves; wave owns 32 q rows (2 sub-blocks of 16). KV tile = 64.
// S^T = mfma(A=K, B=Q): lane ln15 = q row; kv = cb*16 + lg*4 + r.
//   -> softmax: in-lane reduce + shfl_xor(16,32); scalar m/l per lane.
// P^T via per-wave swizzled LDS [q][kv]; O^T = mfma(A=V^T, B=P^T).
// LDS: Ks[64][64], Vt[64][64], Ps[4][32][64]; XOR-swizzle ((row&7)<<4) on
// 16B chunks; staged by global_load_lds with pre-swizzled SOURCE (rule 21).
// ---------------------------------------------------------------------------
__global__ __launch_bounds__(256) void attn_bf16(const __hip_bfloat16* __restrict__ Q,
                                                 const __hip_bfloat16* __restrict__ K,
                                                 const __hip_bfloat16* __restrict__ VT,
                                                 __hip_bfloat16* __restrict__ CTX) {
  __shared__ __hip_bfloat16 Ks[64 * 64];
  __shared__ __hip_bfloat16 Vt[64 * 64];
  __shared__ __hip_bfloat16 Ps[4 * 32 * 64];

  const int tid = threadIdx.x;
  const int wave = tid >> 6, lane = tid & 63;
  const int ln15 = lane & 15, lg = lane >> 4;
  const unsigned swz = (unsigned)((ln15 & 7) << 4);

  // XCD swizzle: 512 blocks, 64 consecutive work-items per XCD -> a head's
  // 16 q-blocks share one XCD's L2 (K/V per head = 512 KB < 4 MB L2).
  const int bid = blockIdx.x;
  const int work = (bid & 7) * 64 + (bid >> 3);
  const int qb = work & 15;          // q-block (128 rows)
  const int bh = work >> 4;          // 0..31

  const __hip_bfloat16* Qh = Q + (size_t)bh * SEQ * HD;
  const __hip_bfloat16* Kh = K + (size_t)bh * SEQ * HD;
  const __hip_bfloat16* Vh = VT + (size_t)bh * HD * SEQ;
  __hip_bfloat16* Pw = Ps + wave * 32 * 64;

  // Q fragments (B-operand layout == A layout: lane ln15 = q row)
  s16x8 aq[2][2];
#pragma unroll
  for (int qs = 0; qs < 2; qs++) {
    const int qrow = qb * 128 + wave * 32 + qs * 16 + ln15;
#pragma unroll
    for (int kb = 0; kb < 2; kb++)
      aq[qs][kb] = *(const s16x8*)&Qh[(size_t)qrow * HD + kb * 32 + lg * 8];
  }

  f32x4 acc_o[2][4];
#pragma unroll
  for (int qs = 0; qs < 2; qs++)
#pragma unroll
    for (int db = 0; db < 4; db++) acc_o[qs][db] = (f32x4){0.f, 0.f, 0.f, 0.f};
  float m_[2] = {-1e30f, -1e30f};
  float l_[2] = {0.f, 0.f};

  for (int kt = 0; kt < SEQ / 64; kt++) {
    __syncthreads();  // prev tile done reading Ks/Vt
    // stage K [kv][d] and V^T [d][kv]: linear LDS dest, pre-swizzled source
#pragma unroll
    for (int c = 0; c < 2; c++) {
      const int row = c * 32 + (tid >> 3);
      const int colb = ((tid & 7) * 16) ^ ((row & 7) << 4);
      __builtin_amdgcn_global_load_lds(
          (GBuf*)((const char*)Kh + ((size_t)(kt * 64 + row) * HD) * 2 + colb),
          (LBuf*)((char*)Ks + c * 4096 + tid * 16), 16, 0, 0);
      __builtin_amdgcn_global_load_lds(
          (GBuf*)((const char*)Vh + ((size_t)row * SEQ + kt * 64) * 2 + colb),
          (LBuf*)((char*)Vt + c * 4096 + tid * 16), 16, 0, 0);
    }
    __syncthreads();  // tiles visible (vmcnt drained by barrier)

    // S^T: A = K rows (fresh per cb), B = Q regs (reused across qs)
    f32x4 s[2][4];
#pragma unroll
    for (int qs = 0; qs < 2; qs++)
#pragma unroll
      for (int cb = 0; cb < 4; cb++) s[qs][cb] = (f32x4){0.f, 0.f, 0.f, 0.f};
#pragma unroll
    for (int cb = 0; cb < 4; cb++) {
      const int krow = cb * 16 + ln15;
#pragma unroll
      for (int kb = 0; kb < 2; kb++) {
        const s16x8 ak =
            *(const s16x8*)((const char*)Ks + krow * 128 + ((kb * 64 + lg * 16) ^ swz));
#pragma unroll
        for (int qs = 0; qs < 2; qs++)
          s[qs][cb] = __builtin_amdgcn_mfma_f32_16x16x32_bf16(ak, aq[qs][kb], s[qs][cb], 0, 0, 0);
      }
    }

    // online softmax (exp2 domain; q = ln15 is lane-local)
#pragma unroll
    for (int qs = 0; qs < 2; qs++) {
      float tm = -1e30f;
#pragma unroll
      for (int cb = 0; cb < 4; cb++)
        tm = fmaxf(tm, fmaxf(fmaxf(s[qs][cb][0], s[qs][cb][1]),
                             fmaxf(s[qs][cb][2], s[qs][cb][3])));
      tm = fmaxf(tm, __shfl_xor(tm, 16));
      tm = fmaxf(tm, __shfl_xor(tm, 32));
      const float mnew = fmaxf(m_[qs], tm);
      const float fs = exp2f(m_[qs] - mnew);
      m_[qs] = mnew;
      float sum = 0.f;
#pragma unroll
      for (int cb = 0; cb < 4; cb++)
#pragma unroll
        for (int r = 0; r < 4; r++) {
          const float p = exp2f(s[qs][cb][r] - mnew);
          s[qs][cb][r] = p;
          sum += p;
        }
      sum += __shfl_xor(sum, 16);
      sum += __shfl_xor(sum, 32);
      l_[qs] = l_[qs] * fs + sum;
#pragma unroll
      for (int db = 0; db < 4; db++)
#pragma unroll
        for (int r = 0; r < 4; r++) acc_o[qs][db][r] *= fs;
      // P -> per-wave LDS [q][kv], swizzled (same-wave RAW: no barrier)
      const int prow = qs * 16 + ln15;
#pragma unroll
      for (int cb = 0; cb < 4; cb++)
#pragma unroll
        for (int r = 0; r < 4; r++) {
          const int kv2 = (cb * 16 + lg * 4 + r) * 2;
          *(__hip_bfloat16*)((char*)Pw + prow * 128 + (kv2 ^ swz)) =
              __float2bfloat16(s[qs][cb][r]);
        }
    }

    // O^T += V^T . P^T
#pragma unroll
    for (int kb = 0; kb < 2; kb++) {
      s16x8 bp[2];
#pragma unroll
      for (int qs = 0; qs < 2; qs++) {
        const int prow = qs * 16 + ln15;
        bp[qs] = *(const s16x8*)((const char*)Pw + prow * 128 + ((kb * 64 + lg * 16) ^ swz));
      }
#pragma unroll
      for (int db = 0; db < 4; db++) {
        const int vrow = db * 16 + ln15;
        const s16x8 av =
            *(const s16x8*)((const char*)Vt + vrow * 128 + ((kb * 64 + lg * 16) ^ swz));
#pragma unroll
        for (int qs = 0; qs < 2; qs++)
          acc_o[qs][db] = __builtin_amdgcn_mfma_f32_16x16x32_bf16(av, bp[qs], acc_o[qs][db], 0, 0, 0);
      }
    }
  }

  // epilogue: O[q][d] = acc_o^T / l, packed 4-elem bf16 stores
  const int b = bh / NH, h = bh % NH;
#pragma unroll
  for (int qs = 0; qs < 2; qs++) {
    const float inv = 1.0f / l_[qs];
    const int n = qb * 128 + wave * 32 + qs * 16 + ln15;
    __hip_bfloat16* dst = &CTX[((size_t)(b * SEQ + n)) * ED + h * HD + lg * 4];
#pragma unroll
    for (int db = 0; db < 4; db++) {
      union { s16x4 v; __hip_bfloat16 hh[4]; } pk;
#pragma unroll
      for (int r = 0; r < 4; r++) pk.hh[r] = __float2bfloat16(acc_o[qs][db][r] * inv);
      *(s16x4*)&dst[db * 16] = pk.v;
    }
  }
}

// ---------------------------------------------------------------------------
extern "C" void kernel_launch(void* const* d_in, const int* in_sizes, int n_in,
                              void* d_out, int out_size, void* d_ws, size_t ws_size,
                              hipStream_t stream) {
  const float* x = (const float*)d_in[0];
  const float* wq = (const float*)d_in[1];
  const float* bq = (const float*)d_in[2];
  const float* wk = (const float*)d_in[3];
  const float* bk = (const float*)d_in[4];
  const float* wv = (const float*)d_in[5];
  const float* bv = (const float*)d_in[6];
  const float* wo = (const float*)d_in[7];
  const float* bo = (const float*)d_in[8];
  float* out = (float*)d_out;

  const int BN = in_sizes[0] / ED;  // 4096

  char* w = (char*)d_ws;
  __hip_bfloat16* xbf = (__hip_bfloat16*)(w);
  __hip_bfloat16* wqb = (__hip_bfloat16*)(w + (8 << 20));
  __hip_bfloat16* wkb = (__hip_bfloat16*)(w + (10 << 20));
  __hip_bfloat16* wvb = (__hip_bfloat16*)(w + (12 << 20));
  __hip_bfloat16* wob = (__hip_bfloat16*)(w + (14 << 20));
  __hip_bfloat16* Qb = (__hip_bfloat16*)(w + (16 << 20));
  __hip_bfloat16* Kb = (__hip_bfloat16*)(w + (24 << 20));
  __hip_bfloat16* VTb = (__hip_bfloat16*)(w + (32 << 20));
  __hip_bfloat16* CTXb = (__hip_bfloat16*)(w + (40 << 20));

  cvt5<<<1024, 256, 0, stream>>>(x, wq, wk, wv, wo, xbf, wqb, wkb, wvb, wob,
                                 BN * ED, ED * ED, ED * ED, ED * ED, ED * ED);

  const dim3 blk(256);
  gemm_qkv<<<dim3(ED / 128, BN / 128, 3), blk, 0, stream>>>(
      xbf, wqb, bq, wkb, bk, wvb, bv, Qb, Kb, VTb);

  attn_bf16<<<dim3(512), blk, 0, stream>>>(Qb, Kb, VTb, CTXb);

  gemm_out<<<dim3(ED / 128, BN / 128), blk, 0, stream>>>(CTXb, wob, bo, out);
}

// Round 5
// 243.843 us; speedup vs baseline: 6.2739x; 1.0809x over previous
//
#include <hip/hip_runtime.h>
#include <hip/hip_bf16.h>

#define ED 1024
#define NH 16
#define HD 64
#define SEQ 2048

typedef float f32x4 __attribute__((ext_vector_type(4)));
typedef float f32x16 __attribute__((ext_vector_type(16)));
typedef short s16x8 __attribute__((ext_vector_type(8)));
typedef short s16x4 __attribute__((ext_vector_type(4)));
typedef __attribute__((address_space(1))) const unsigned int GBuf;
typedef __attribute__((address_space(3))) unsigned int LBuf;

#define QSC 0.18033688011112042f  // 0.125 * log2(e): fold softmax scale + exp2 base

union BF8 { s16x8 v; __hip_bfloat16 h[8]; };

// v_cvt_pk_bf16_f32: pack 2 f32 -> 2 bf16 in one u32 (no builtin on gfx950)
__device__ __forceinline__ unsigned cvt_pk_bf16(float lo, float hi) {
  unsigned r;
  asm("v_cvt_pk_bf16_f32 %0, %1, %2" : "=v"(r) : "v"(lo), "v"(hi));
  return r;
}

// Build one PV A/B-fragment (8 bf16, K=16) from this lane's 8 f32 P values.
// After S^T (32x32 C layout) lane-lo holds kv {0,1,2,3,8,9,10,11}, lane-hi
// {4,5,6,7,12,13,14,15}. permlane32_swap (swaps a.hi-lanes <-> b.lo-lanes)
// redistributes so lane-lo has kv 0..7, lane-hi kv 8..15 = the k-split the
// 32x32x16 fragment needs.
__device__ __forceinline__ s16x8 pack_pfrag(float p0, float p1, float p2, float p3,
                                            float p4, float p5, float p6, float p7) {
  unsigned w0 = cvt_pk_bf16(p0, p1), w1 = cvt_pk_bf16(p2, p3);
  unsigned w2 = cvt_pk_bf16(p4, p5), w3 = cvt_pk_bf16(p6, p7);
  asm("v_permlane32_swap_b32 %0, %1" : "+v"(w0), "+v"(w2));
  asm("v_permlane32_swap_b32 %0, %1" : "+v"(w1), "+v"(w3));
  union { unsigned u[4]; s16x8 v; } r;
  r.u[0] = w0; r.u[1] = w1; r.u[2] = w2; r.u[3] = w3;
  return r.v;
}

// ---------------------------------------------------------------------------
// fp32 -> bf16 conversion (vectorized, grid-stride)
// ---------------------------------------------------------------------------
__device__ inline void cvt_one(const float* __restrict__ s, __hip_bfloat16* __restrict__ d,
                               int n, int t, int stride) {
  const int n8 = n >> 3;
  for (int i = t; i < n8; i += stride) {
    const float4 u = ((const float4*)s)[2 * i];
    const float4 v = ((const float4*)s)[2 * i + 1];
    BF8 o;
    o.h[0] = __float2bfloat16(u.x); o.h[1] = __float2bfloat16(u.y);
    o.h[2] = __float2bfloat16(u.z); o.h[3] = __float2bfloat16(u.w);
    o.h[4] = __float2bfloat16(v.x); o.h[5] = __float2bfloat16(v.y);
    o.h[6] = __float2bfloat16(v.z); o.h[7] = __float2bfloat16(v.w);
    ((s16x8*)d)[i] = o.v;
  }
}

__global__ __launch_bounds__(256) void cvt5(const float* s0, const float* s1, const float* s2,
                                            const float* s3, const float* s4,
                                            __hip_bfloat16* d0, __hip_bfloat16* d1,
                                            __hip_bfloat16* d2, __hip_bfloat16* d3,
                                            __hip_bfloat16* d4,
                                            int n0, int n1, int n2, int n3, int n4) {
  const int stride = gridDim.x * blockDim.x;
  const int t = blockIdx.x * blockDim.x + threadIdx.x;
  cvt_one(s0, d0, n0, t, stride);
  cvt_one(s1, d1, n1, t, stride);
  cvt_one(s2, d2, n2, t, stride);
  cvt_one(s3, d3, n3, t, stride);
  cvt_one(s4, d4, n4, t, stride);
}

// ---------------------------------------------------------------------------
// Fused QKV GEMM. z = blockIdx.z selects {Q,K,V}. (unchanged from round 4)
// ---------------------------------------------------------------------------
__global__ __launch_bounds__(256) void gemm_qkv(const __hip_bfloat16* __restrict__ A,
                                                const __hip_bfloat16* __restrict__ wq,
                                                const float* __restrict__ bq,
                                                const __hip_bfloat16* __restrict__ wk,
                                                const float* __restrict__ bk,
                                                const __hip_bfloat16* __restrict__ wv,
                                                const float* __restrict__ bv,
                                                __hip_bfloat16* __restrict__ Qo,
                                                __hip_bfloat16* __restrict__ Ko,
                                                __hip_bfloat16* __restrict__ Vo) {
  __shared__ __hip_bfloat16 As[128 * 64];
  __shared__ __hip_bfloat16 Bs[128 * 64];

  const int z = blockIdx.z;
  const __hip_bfloat16* W = (z == 0) ? wq : (z == 1) ? wk : wv;
  const float* bias = (z == 0) ? bq : (z == 1) ? bk : bv;

  const int tid = threadIdx.x;
  const int wave = tid >> 6, lane = tid & 63;
  const int ln15 = lane & 15, lg = lane >> 4;
  const int m0 = blockIdx.y * 128, n0 = blockIdx.x * 128;
  const int wr = (wave >> 1) * 64, wc = (wave & 1) * 64;

  f32x4 acc[4][4];
#pragma unroll
  for (int i = 0; i < 4; i++)
#pragma unroll
    for (int j = 0; j < 4; j++) acc[i][j] = (f32x4){0.f, 0.f, 0.f, 0.f};

  const int srow = tid >> 3;
  const int sk = (tid & 7) * 8;

  for (int k0 = 0; k0 < ED; k0 += 64) {
    __syncthreads();
#pragma unroll
    for (int c = 0; c < 4; c++) {
      const int r = c * 32 + srow;
      __builtin_amdgcn_global_load_lds((GBuf*)(A + (size_t)(m0 + r) * ED + k0 + sk),
                                       (LBuf*)((char*)As + c * 4096 + tid * 16), 16, 0, 0);
    }
#pragma unroll
    for (int c = 0; c < 4; c++) {
      const int r = c * 32 + srow;
      __builtin_amdgcn_global_load_lds((GBuf*)(W + (size_t)(n0 + r) * ED + k0 + sk),
                                       (LBuf*)((char*)Bs + c * 4096 + tid * 16), 16, 0, 0);
    }
    __syncthreads();
#pragma unroll
    for (int kb = 0; kb < 2; kb++) {
      const int kof = kb * 32 + lg * 8;
      s16x8 a[4], b[4];
#pragma unroll
      for (int i = 0; i < 4; i++)
        a[i] = *(const s16x8*)&As[(wr + i * 16 + ln15) * 64 + kof];
#pragma unroll
      for (int j = 0; j < 4; j++)
        b[j] = *(const s16x8*)&Bs[(wc + j * 16 + ln15) * 64 + kof];
#pragma unroll
      for (int i = 0; i < 4; i++)
#pragma unroll
        for (int j = 0; j < 4; j++)
          acc[i][j] = __builtin_amdgcn_mfma_f32_16x16x32_bf16(a[i], b[j], acc[i][j], 0, 0, 0);
    }
  }

  const float scale = (z == 0) ? QSC : 1.0f;
  if (z < 2) {
    __hip_bfloat16* out = (z == 0) ? Qo : Ko;
#pragma unroll
    for (int j = 0; j < 4; j++) {
      const int e = n0 + wc + j * 16 + ln15;
      const float bvv = bias[e];
      const int h = e >> 6, hd = e & 63;
#pragma unroll
      for (int i = 0; i < 4; i++) {
#pragma unroll
        for (int r = 0; r < 4; r++) {
          const int m = m0 + wr + i * 16 + lg * 4 + r;
          const int b = m >> 11, n = m & 2047;
          out[(((size_t)(b * NH + h)) * SEQ + n) * HD + hd] =
              __float2bfloat16((acc[i][j][r] + bvv) * scale);
        }
      }
    }
  } else {
#pragma unroll
    for (int j = 0; j < 4; j++) {
      const int e = n0 + wc + j * 16 + ln15;
      const float bvv = bias[e];
      const int h = e >> 6, hd = e & 63;
#pragma unroll
      for (int i = 0; i < 4; i++) {
        const int m = m0 + wr + i * 16 + lg * 4;
        const int b = m >> 11, n = m & 2047;
        union { s16x4 v; __hip_bfloat16 hh[4]; } pk;
#pragma unroll
        for (int r = 0; r < 4; r++) pk.hh[r] = __float2bfloat16(acc[i][j][r] + bvv);
        *(s16x4*)&Vo[(((size_t)(b * NH + h)) * HD + hd) * SEQ + n] = pk.v;
      }
    }
  }
}

// ---------------------------------------------------------------------------
// Output GEMM: out fp32 [M][ED] = CTX @ Wo^T + bo  (unchanged from round 4)
// ---------------------------------------------------------------------------
__global__ __launch_bounds__(256) void gemm_out(const __hip_bfloat16* __restrict__ A,
                                                const __hip_bfloat16* __restrict__ W,
                                                const float* __restrict__ bias,
                                                float* __restrict__ out) {
  __shared__ __hip_bfloat16 As[128 * 64];
  __shared__ __hip_bfloat16 Bs[128 * 64];

  const int tid = threadIdx.x;
  const int wave = tid >> 6, lane = tid & 63;
  const int ln15 = lane & 15, lg = lane >> 4;
  const int m0 = blockIdx.y * 128, n0 = blockIdx.x * 128;
  const int wr = (wave >> 1) * 64, wc = (wave & 1) * 64;

  f32x4 acc[4][4];
#pragma unroll
  for (int i = 0; i < 4; i++)
#pragma unroll
    for (int j = 0; j < 4; j++) acc[i][j] = (f32x4){0.f, 0.f, 0.f, 0.f};

  const int srow = tid >> 3;
  const int sk = (tid & 7) * 8;

  for (int k0 = 0; k0 < ED; k0 += 64) {
    __syncthreads();
#pragma unroll
    for (int c = 0; c < 4; c++) {
      const int r = c * 32 + srow;
      __builtin_amdgcn_global_load_lds((GBuf*)(A + (size_t)(m0 + r) * ED + k0 + sk),
                                       (LBuf*)((char*)As + c * 4096 + tid * 16), 16, 0, 0);
    }
#pragma unroll
    for (int c = 0; c < 4; c++) {
      const int r = c * 32 + srow;
      __builtin_amdgcn_global_load_lds((GBuf*)(W + (size_t)(n0 + r) * ED + k0 + sk),
                                       (LBuf*)((char*)Bs + c * 4096 + tid * 16), 16, 0, 0);
    }
    __syncthreads();
#pragma unroll
    for (int kb = 0; kb < 2; kb++) {
      const int kof = kb * 32 + lg * 8;
      s16x8 a[4], b[4];
#pragma unroll
      for (int i = 0; i < 4; i++)
        a[i] = *(const s16x8*)&As[(wr + i * 16 + ln15) * 64 + kof];
#pragma unroll
      for (int j = 0; j < 4; j++)
        b[j] = *(const s16x8*)&Bs[(wc + j * 16 + ln15) * 64 + kof];
#pragma unroll
      for (int i = 0; i < 4; i++)
#pragma unroll
        for (int j = 0; j < 4; j++)
          acc[i][j] = __builtin_amdgcn_mfma_f32_16x16x32_bf16(a[i], b[j], acc[i][j], 0, 0, 0);
    }
  }

#pragma unroll
  for (int j = 0; j < 4; j++) {
    const int e = n0 + wc + j * 16 + ln15;
    const float bvv = bias[e];
#pragma unroll
    for (int i = 0; i < 4; i++)
#pragma unroll
      for (int r = 0; r < 4; r++) {
        const int m = m0 + wr + i * 16 + lg * 4 + r;
        out[(size_t)m * ED + e] = acc[i][j][r] + bvv;
      }
  }
}

// ---------------------------------------------------------------------------
// Flash attention v3: 32x32x16 MFMA, in-register P (cvt_pk + permlane32_swap),
// double-buffered K/V staging (1 barrier/iter), defer-max (THR=8).
// Q,K: [B*NH][SEQ][HD] bf16 (Q pre-scaled by QSC); VT: [B*NH][HD][SEQ] bf16.
// 4 waves x 32 q rows = 128 q/block. KV tile 64 = 2 kv-subtiles of 32.
// S^T = mfma_32x32x16(A=K, B=Q): C col = q = lane&31 (lane-local row!),
//   row kv = (reg&3) + 8*(reg>>2) + 4*(lane>>5).
// O^T = mfma_32x32x16(A=V^T, B=P^T): C col = q, row d (+32*dh).
// LDS tiles XOR-swizzled on 16B chunks, staged via pre-swizzled global source.
// ---------------------------------------------------------------------------
__global__ __launch_bounds__(256) void attn_bf16(const __hip_bfloat16* __restrict__ Q,
                                                 const __hip_bfloat16* __restrict__ K,
                                                 const __hip_bfloat16* __restrict__ VT,
                                                 __hip_bfloat16* __restrict__ CTX) {
  __shared__ __hip_bfloat16 KsS[2][64 * 64];
  __shared__ __hip_bfloat16 VtS[2][64 * 64];

  const int tid = threadIdx.x;
  const int wave = tid >> 6, lane = tid & 63;
  const int l31 = lane & 31, hi = lane >> 5;
  const int rswz = l31 & 7;

  // XCD swizzle: a head's 16 q-blocks land on one XCD (KV/head = 512 KB < L2)
  const int bid = blockIdx.x;
  const int work = (bid & 7) * 64 + (bid >> 3);
  const int qb = work & 15;
  const int bh = work >> 4;

  const __hip_bfloat16* Qh = Q + (size_t)bh * SEQ * HD;
  const __hip_bfloat16* Kh = K + (size_t)bh * SEQ * HD;
  const __hip_bfloat16* Vh = VT + (size_t)bh * HD * SEQ;

  const int q0 = qb * 128 + wave * 32;

  // Q B-fragments: lane l holds Q[q = q0 + l31][d = kb*16 + hi*8 + 0..7]
  s16x8 aq[4];
#pragma unroll
  for (int kb = 0; kb < 4; kb++)
    aq[kb] = *(const s16x8*)&Qh[(size_t)(q0 + l31) * HD + kb * 16 + hi * 8];

  f32x16 acc0 = {}, acc1 = {};  // O^T: d 0-31 / 32-63, col q = l31
  float m_ = -1e30f, l_ = 0.f;

  auto STAGE = [&](int kt_, int buf_) {
#pragma unroll
    for (int c = 0; c < 2; c++) {
      const int row = c * 32 + (tid >> 3);
      const int colb = ((tid & 7) * 16) ^ ((row & 7) << 4);
      __builtin_amdgcn_global_load_lds(
          (GBuf*)((const char*)Kh + ((size_t)(kt_ * 64 + row) * HD) * 2 + colb),
          (LBuf*)((char*)&KsS[buf_][0] + c * 4096 + tid * 16), 16, 0, 0);
      __builtin_amdgcn_global_load_lds(
          (GBuf*)((const char*)Vh + ((size_t)row * SEQ + kt_ * 64) * 2 + colb),
          (LBuf*)((char*)&VtS[buf_][0] + c * 4096 + tid * 16), 16, 0, 0);
    }
  };

  STAGE(0, 0);

  const int NT = SEQ / 64;
  for (int kt = 0; kt < NT; kt++) {
    const int cur = kt & 1;
    __syncthreads();  // drains vmcnt -> buf[cur] staged; prev iter done reading buf[cur^1]
    if (kt + 1 < NT) STAGE(kt + 1, cur ^ 1);  // in flight during compute

    // ---- S^T = K . Q^T : two 32-kv subtiles
    f32x16 s0 = {}, s1 = {};
#pragma unroll
    for (int kb = 0; kb < 4; kb++) {
      const int coff = ((kb * 2 + hi) ^ rswz) << 4;
      const s16x8 ak0 = *(const s16x8*)((const char*)&KsS[cur][0] + l31 * 128 + coff);
      const s16x8 ak1 = *(const s16x8*)((const char*)&KsS[cur][0] + (32 + l31) * 128 + coff);
      s0 = __builtin_amdgcn_mfma_f32_32x32x16_bf16(ak0, aq[kb], s0, 0, 0, 0);
      s1 = __builtin_amdgcn_mfma_f32_32x32x16_bf16(ak1, aq[kb], s1, 0, 0, 0);
    }

    // ---- online softmax (q lane-local; 32 scores in regs)
    float t8[8];
#pragma unroll
    for (int i = 0; i < 8; i++)
      t8[i] = fmaxf(fmaxf(s0[i], s0[i + 8]), fmaxf(s1[i], s1[i + 8]));
    float tm = fmaxf(fmaxf(fmaxf(t8[0], t8[1]), fmaxf(t8[2], t8[3])),
                     fmaxf(fmaxf(t8[4], t8[5]), fmaxf(t8[6], t8[7])));
    tm = fmaxf(tm, __shfl_xor(tm, 32));

    if (!__all(tm - m_ <= 8.0f)) {  // defer-max: skip rescale for small growth
      const float mnew = fmaxf(m_, tm);
      const float fs = exp2f(m_ - mnew);
      m_ = mnew;
      l_ *= fs;
#pragma unroll
      for (int r = 0; r < 16; r++) { acc0[r] *= fs; acc1[r] *= fs; }
    }

#pragma unroll
    for (int r = 0; r < 16; r++) {
      s0[r] = exp2f(s0[r] - m_);
      s1[r] = exp2f(s1[r] - m_);
    }
    float sa[8];
#pragma unroll
    for (int i = 0; i < 8; i++) sa[i] = (s0[i] + s0[i + 8]) + (s1[i] + s1[i + 8]);
    float sum = ((sa[0] + sa[1]) + (sa[2] + sa[3])) + ((sa[4] + sa[5]) + (sa[6] + sa[7]));
    sum += __shfl_xor(sum, 32);
    l_ += sum;

    // ---- P fragments in registers (16 cvt_pk + 8 permlane32_swap)
    s16x8 pa[4];
    pa[0] = pack_pfrag(s0[0], s0[1], s0[2], s0[3], s0[4], s0[5], s0[6], s0[7]);
    pa[1] = pack_pfrag(s0[8], s0[9], s0[10], s0[11], s0[12], s0[13], s0[14], s0[15]);
    pa[2] = pack_pfrag(s1[0], s1[1], s1[2], s1[3], s1[4], s1[5], s1[6], s1[7]);
    pa[3] = pack_pfrag(s1[8], s1[9], s1[10], s1[11], s1[12], s1[13], s1[14], s1[15]);

    // ---- O^T += V^T . P^T
#pragma unroll
    for (int kp = 0; kp < 4; kp++) {
      const int coff = ((kp * 2 + hi) ^ rswz) << 4;
      const s16x8 av0 = *(const s16x8*)((const char*)&VtS[cur][0] + l31 * 128 + coff);
      const s16x8 av1 = *(const s16x8*)((const char*)&VtS[cur][0] + (32 + l31) * 128 + coff);
      acc0 = __builtin_amdgcn_mfma_f32_32x32x16_bf16(av0, pa[kp], acc0, 0, 0, 0);
      acc1 = __builtin_amdgcn_mfma_f32_32x32x16_bf16(av1, pa[kp], acc1, 0, 0, 0);
    }
  }

  // ---- epilogue: O[q][d] = acc^T / l ; d = dh*32 + 8g + 4hi + (0..3)
  const float inv = 1.0f / l_;
  const int b = bh / NH, h = bh % NH;
  const int n = q0 + l31;
  __hip_bfloat16* dst = &CTX[((size_t)(b * SEQ + n)) * ED + h * HD];
#pragma unroll
  for (int g = 0; g < 4; g++) {
    union { s16x4 v; __hip_bfloat16 hh[4]; } p0, p1;
#pragma unroll
    for (int r = 0; r < 4; r++) {
      p0.hh[r] = __float2bfloat16(acc0[4 * g + r] * inv);
      p1.hh[r] = __float2bfloat16(acc1[4 * g + r] * inv);
    }
    *(s16x4*)&dst[8 * g + 4 * hi] = p0.v;
    *(s16x4*)&dst[32 + 8 * g + 4 * hi] = p1.v;
  }
}

// ---------------------------------------------------------------------------
extern "C" void kernel_launch(void* const* d_in, const int* in_sizes, int n_in,
                              void* d_out, int out_size, void* d_ws, size_t ws_size,
                              hipStream_t stream) {
  const float* x = (const float*)d_in[0];
  const float* wq = (const float*)d_in[1];
  const float* bq = (const float*)d_in[2];
  const float* wk = (const float*)d_in[3];
  const float* bk = (const float*)d_in[4];
  const float* wv = (const float*)d_in[5];
  const float* bv = (const float*)d_in[6];
  const float* wo = (const float*)d_in[7];
  const float* bo = (const float*)d_in[8];
  float* out = (float*)d_out;

  const int BN = in_sizes[0] / ED;  // 4096

  char* w = (char*)d_ws;
  __hip_bfloat16* xbf = (__hip_bfloat16*)(w);
  __hip_bfloat16* wqb = (__hip_bfloat16*)(w + (8 << 20));
  __hip_bfloat16* wkb = (__hip_bfloat16*)(w + (10 << 20));
  __hip_bfloat16* wvb = (__hip_bfloat16*)(w + (12 << 20));
  __hip_bfloat16* wob = (__hip_bfloat16*)(w + (14 << 20));
  __hip_bfloat16* Qb = (__hip_bfloat16*)(w + (16 << 20));
  __hip_bfloat16* Kb = (__hip_bfloat16*)(w + (24 << 20));
  __hip_bfloat16* VTb = (__hip_bfloat16*)(w + (32 << 20));
  __hip_bfloat16* CTXb = (__hip_bfloat16*)(w + (40 << 20));

  cvt5<<<1024, 256, 0, stream>>>(x, wq, wk, wv, wo, xbf, wqb, wkb, wvb, wob,
                                 BN * ED, ED * ED, ED * ED, ED * ED, ED * ED);

  const dim3 blk(256);
  gemm_qkv<<<dim3(ED / 128, BN / 128, 3), blk, 0, stream>>>(
      xbf, wqb, bq, wkb, bk, wvb, bv, Qb, Kb, VTb);

  attn_bf16<<<dim3(512), blk, 0, stream>>>(Qb, Kb, VTb, CTXb);

  gemm_out<<<dim3(ED / 128, BN / 128), blk, 0, stream>>>(CTXb, wob, bo, out);
}

// Round 6
// 237.744 us; speedup vs baseline: 6.4349x; 1.0257x over previous
//
#include <hip/hip_runtime.h>
#include <hip/hip_bf16.h>

#define ED 1024
#define NH 16
#define HD 64
#define SEQ 2048

typedef float f32x4 __attribute__((ext_vector_type(4)));
typedef float f32x16 __attribute__((ext_vector_type(16)));
typedef short s16x8 __attribute__((ext_vector_type(8)));
typedef short s16x4 __attribute__((ext_vector_type(4)));
typedef __attribute__((address_space(1))) const unsigned int GBuf;
typedef __attribute__((address_space(3))) unsigned int LBuf;

#define QSC 0.18033688011112042f  // 0.125 * log2(e): fold softmax scale + exp2 base

union BF8 { s16x8 v; __hip_bfloat16 h[8]; };

// v_cvt_pk_bf16_f32: pack 2 f32 -> 2 bf16 in one u32 (no builtin on gfx950)
__device__ __forceinline__ unsigned cvt_pk_bf16(float lo, float hi) {
  unsigned r;
  asm("v_cvt_pk_bf16_f32 %0, %1, %2" : "=v"(r) : "v"(lo), "v"(hi));
  return r;
}

// Build one PV A/B-fragment (8 bf16, K=16) from this lane's 8 f32 P values.
__device__ __forceinline__ s16x8 pack_pfrag(float p0, float p1, float p2, float p3,
                                            float p4, float p5, float p6, float p7) {
  unsigned w0 = cvt_pk_bf16(p0, p1), w1 = cvt_pk_bf16(p2, p3);
  unsigned w2 = cvt_pk_bf16(p4, p5), w3 = cvt_pk_bf16(p6, p7);
  asm("v_permlane32_swap_b32 %0, %1" : "+v"(w0), "+v"(w2));
  asm("v_permlane32_swap_b32 %0, %1" : "+v"(w1), "+v"(w3));
  union { unsigned u[4]; s16x8 v; } r;
  r.u[0] = w0; r.u[1] = w1; r.u[2] = w2; r.u[3] = w3;
  return r.v;
}

// ---------------------------------------------------------------------------
// fp32 -> bf16 conversion (vectorized, grid-stride)
// ---------------------------------------------------------------------------
__device__ inline void cvt_one(const float* __restrict__ s, __hip_bfloat16* __restrict__ d,
                               int n, int t, int stride) {
  const int n8 = n >> 3;
  for (int i = t; i < n8; i += stride) {
    const float4 u = ((const float4*)s)[2 * i];
    const float4 v = ((const float4*)s)[2 * i + 1];
    BF8 o;
    o.h[0] = __float2bfloat16(u.x); o.h[1] = __float2bfloat16(u.y);
    o.h[2] = __float2bfloat16(u.z); o.h[3] = __float2bfloat16(u.w);
    o.h[4] = __float2bfloat16(v.x); o.h[5] = __float2bfloat16(v.y);
    o.h[6] = __float2bfloat16(v.z); o.h[7] = __float2bfloat16(v.w);
    ((s16x8*)d)[i] = o.v;
  }
}

__global__ __launch_bounds__(256) void cvt5(const float* s0, const float* s1, const float* s2,
                                            const float* s3, const float* s4,
                                            __hip_bfloat16* d0, __hip_bfloat16* d1,
                                            __hip_bfloat16* d2, __hip_bfloat16* d3,
                                            __hip_bfloat16* d4,
                                            int n0, int n1, int n2, int n3, int n4) {
  const int stride = gridDim.x * blockDim.x;
  const int t = blockIdx.x * blockDim.x + threadIdx.x;
  cvt_one(s0, d0, n0, t, stride);
  cvt_one(s1, d1, n1, t, stride);
  cvt_one(s2, d2, n2, t, stride);
  cvt_one(s3, d3, n3, t, stride);
  cvt_one(s4, d4, n4, t, stride);
}

// ---------------------------------------------------------------------------
// Fused QKV GEMM, 2-phase double-buffered (STAGE t+1 before compute t, one
// __syncthreads per K-tile) + bijective XCD chunk swizzle.
// z<2 : out bf16 [B*NH][SEQ][HD], value (acc+bias)*scale  (Q: scale=QSC)
// z==2: out bf16 V^T [B*NH][HD][SEQ], packed 4-contiguous stores
// ---------------------------------------------------------------------------
__global__ __launch_bounds__(256) void gemm_qkv(const __hip_bfloat16* __restrict__ A,
                                                const __hip_bfloat16* __restrict__ wq,
                                                const float* __restrict__ bq,
                                                const __hip_bfloat16* __restrict__ wk,
                                                const float* __restrict__ bk,
                                                const __hip_bfloat16* __restrict__ wv,
                                                const float* __restrict__ bv,
                                                __hip_bfloat16* __restrict__ Qo,
                                                __hip_bfloat16* __restrict__ Ko,
                                                __hip_bfloat16* __restrict__ Vo) {
  __shared__ __hip_bfloat16 As[2][128 * 64];
  __shared__ __hip_bfloat16 Bs[2][128 * 64];

  // XCD chunk swizzle: 768 blocks -> each XCD owns 96 consecutive work ids
  // (one z + 12 A-panels: ~5 MB working set per XCD L2).
  const int lin = (blockIdx.z * 32 + blockIdx.y) * 8 + blockIdx.x;
  const int work = (lin & 7) * 96 + (lin >> 3);
  const int z = work >> 8;
  const int rem = work & 255;
  const int m0 = (rem >> 3) * 128, n0 = (rem & 7) * 128;

  const __hip_bfloat16* W = (z == 0) ? wq : (z == 1) ? wk : wv;
  const float* bias = (z == 0) ? bq : (z == 1) ? bk : bv;

  const int tid = threadIdx.x;
  const int wave = tid >> 6, lane = tid & 63;
  const int ln15 = lane & 15, lg = lane >> 4;
  const int wr = (wave >> 1) * 64, wc = (wave & 1) * 64;

  f32x4 acc[4][4];
#pragma unroll
  for (int i = 0; i < 4; i++)
#pragma unroll
    for (int j = 0; j < 4; j++) acc[i][j] = (f32x4){0.f, 0.f, 0.f, 0.f};

  const int srow = tid >> 3;
  const int sk = (tid & 7) * 8;

  auto STAGE = [&](int t, int buf) {
    const int k0 = t * 64;
#pragma unroll
    for (int c = 0; c < 4; c++) {
      const int r = c * 32 + srow;
      __builtin_amdgcn_global_load_lds((GBuf*)(A + (size_t)(m0 + r) * ED + k0 + sk),
                                       (LBuf*)((char*)&As[buf][0] + c * 4096 + tid * 16), 16, 0, 0);
      __builtin_amdgcn_global_load_lds((GBuf*)(W + (size_t)(n0 + r) * ED + k0 + sk),
                                       (LBuf*)((char*)&Bs[buf][0] + c * 4096 + tid * 16), 16, 0, 0);
    }
  };

  const int NT = ED / 64;  // 16
  STAGE(0, 0);
  __syncthreads();
  for (int t = 0; t < NT; t++) {
    const int cur = t & 1;
    if (t + 1 < NT) STAGE(t + 1, cur ^ 1);  // fly under compute
    __builtin_amdgcn_s_setprio(1);
#pragma unroll
    for (int kb = 0; kb < 2; kb++) {
      const int kof = kb * 32 + lg * 8;
      s16x8 a[4], b[4];
#pragma unroll
      for (int i = 0; i < 4; i++)
        a[i] = *(const s16x8*)&As[cur][(wr + i * 16 + ln15) * 64 + kof];
#pragma unroll
      for (int j = 0; j < 4; j++)
        b[j] = *(const s16x8*)&Bs[cur][(wc + j * 16 + ln15) * 64 + kof];
#pragma unroll
      for (int i = 0; i < 4; i++)
#pragma unroll
        for (int j = 0; j < 4; j++)
          acc[i][j] = __builtin_amdgcn_mfma_f32_16x16x32_bf16(a[i], b[j], acc[i][j], 0, 0, 0);
    }
    __builtin_amdgcn_s_setprio(0);
    __syncthreads();  // drains vmcnt -> buf[cur^1] staged; gates buffer reuse
  }

  const float scale = (z == 0) ? QSC : 1.0f;
  if (z < 2) {
    __hip_bfloat16* out = (z == 0) ? Qo : Ko;
#pragma unroll
    for (int j = 0; j < 4; j++) {
      const int e = n0 + wc + j * 16 + ln15;
      const float bvv = bias[e];
      const int h = e >> 6, hd = e & 63;
#pragma unroll
      for (int i = 0; i < 4; i++) {
#pragma unroll
        for (int r = 0; r < 4; r++) {
          const int m = m0 + wr + i * 16 + lg * 4 + r;
          const int b = m >> 11, n = m & 2047;
          out[(((size_t)(b * NH + h)) * SEQ + n) * HD + hd] =
              __float2bfloat16((acc[i][j][r] + bvv) * scale);
        }
      }
    }
  } else {
#pragma unroll
    for (int j = 0; j < 4; j++) {
      const int e = n0 + wc + j * 16 + ln15;
      const float bvv = bias[e];
      const int h = e >> 6, hd = e & 63;
#pragma unroll
      for (int i = 0; i < 4; i++) {
        const int m = m0 + wr + i * 16 + lg * 4;
        const int b = m >> 11, n = m & 2047;
        union { s16x4 v; __hip_bfloat16 hh[4]; } pk;
#pragma unroll
        for (int r = 0; r < 4; r++) pk.hh[r] = __float2bfloat16(acc[i][j][r] + bvv);
        *(s16x4*)&Vo[(((size_t)(b * NH + h)) * HD + hd) * SEQ + n] = pk.v;
      }
    }
  }
}

// ---------------------------------------------------------------------------
// Output GEMM, same 2-phase dbuf structure: out fp32 [M][ED] = CTX @ Wo^T + bo
// ---------------------------------------------------------------------------
__global__ __launch_bounds__(256) void gemm_out(const __hip_bfloat16* __restrict__ A,
                                                const __hip_bfloat16* __restrict__ W,
                                                const float* __restrict__ bias,
                                                float* __restrict__ out) {
  __shared__ __hip_bfloat16 As[2][128 * 64];
  __shared__ __hip_bfloat16 Bs[2][128 * 64];

  const int lin = blockIdx.y * 8 + blockIdx.x;
  const int work = (lin & 7) * 32 + (lin >> 3);  // 256 blocks, 32/XCD
  const int m0 = (work >> 3) * 128, n0 = (work & 7) * 128;

  const int tid = threadIdx.x;
  const int wave = tid >> 6, lane = tid & 63;
  const int ln15 = lane & 15, lg = lane >> 4;
  const int wr = (wave >> 1) * 64, wc = (wave & 1) * 64;

  f32x4 acc[4][4];
#pragma unroll
  for (int i = 0; i < 4; i++)
#pragma unroll
    for (int j = 0; j < 4; j++) acc[i][j] = (f32x4){0.f, 0.f, 0.f, 0.f};

  const int srow = tid >> 3;
  const int sk = (tid & 7) * 8;

  auto STAGE = [&](int t, int buf) {
    const int k0 = t * 64;
#pragma unroll
    for (int c = 0; c < 4; c++) {
      const int r = c * 32 + srow;
      __builtin_amdgcn_global_load_lds((GBuf*)(A + (size_t)(m0 + r) * ED + k0 + sk),
                                       (LBuf*)((char*)&As[buf][0] + c * 4096 + tid * 16), 16, 0, 0);
      __builtin_amdgcn_global_load_lds((GBuf*)(W + (size_t)(n0 + r) * ED + k0 + sk),
                                       (LBuf*)((char*)&Bs[buf][0] + c * 4096 + tid * 16), 16, 0, 0);
    }
  };

  const int NT = ED / 64;
  STAGE(0, 0);
  __syncthreads();
  for (int t = 0; t < NT; t++) {
    const int cur = t & 1;
    if (t + 1 < NT) STAGE(t + 1, cur ^ 1);
    __builtin_amdgcn_s_setprio(1);
#pragma unroll
    for (int kb = 0; kb < 2; kb++) {
      const int kof = kb * 32 + lg * 8;
      s16x8 a[4], b[4];
#pragma unroll
      for (int i = 0; i < 4; i++)
        a[i] = *(const s16x8*)&As[cur][(wr + i * 16 + ln15) * 64 + kof];
#pragma unroll
      for (int j = 0; j < 4; j++)
        b[j] = *(const s16x8*)&Bs[cur][(wc + j * 16 + ln15) * 64 + kof];
#pragma unroll
      for (int i = 0; i < 4; i++)
#pragma unroll
        for (int j = 0; j < 4; j++)
          acc[i][j] = __builtin_amdgcn_mfma_f32_16x16x32_bf16(a[i], b[j], acc[i][j], 0, 0, 0);
    }
    __builtin_amdgcn_s_setprio(0);
    __syncthreads();
  }

#pragma unroll
  for (int j = 0; j < 4; j++) {
    const int e = n0 + wc + j * 16 + ln15;
    const float bvv = bias[e];
#pragma unroll
    for (int i = 0; i < 4; i++)
#pragma unroll
      for (int r = 0; r < 4; r++) {
        const int m = m0 + wr + i * 16 + lg * 4 + r;
        out[(size_t)m * ED + e] = acc[i][j][r] + bvv;
      }
  }
}

// ---------------------------------------------------------------------------
// Flash attention v4: 32x32x16 MFMA, in-register P, depth-2 prefetch with
// counted vmcnt(4) + raw s_barrier (3-buffer LDS ring), setprio on MFMA.
// ---------------------------------------------------------------------------
__global__ __launch_bounds__(256) void attn_bf16(const __hip_bfloat16* __restrict__ Q,
                                                 const __hip_bfloat16* __restrict__ K,
                                                 const __hip_bfloat16* __restrict__ VT,
                                                 __hip_bfloat16* __restrict__ CTX) {
  __shared__ __hip_bfloat16 KsS[3][64 * 64];
  __shared__ __hip_bfloat16 VtS[3][64 * 64];

  const int tid = threadIdx.x;
  const int wave = tid >> 6, lane = tid & 63;
  const int l31 = lane & 31, hi = lane >> 5;
  const int rswz = l31 & 7;

  const int bid = blockIdx.x;
  const int work = (bid & 7) * 64 + (bid >> 3);
  const int qb = work & 15;
  const int bh = work >> 4;

  const __hip_bfloat16* Qh = Q + (size_t)bh * SEQ * HD;
  const __hip_bfloat16* Kh = K + (size_t)bh * SEQ * HD;
  const __hip_bfloat16* Vh = VT + (size_t)bh * HD * SEQ;

  const int q0 = qb * 128 + wave * 32;

  s16x8 aq[4];
#pragma unroll
  for (int kb = 0; kb < 4; kb++)
    aq[kb] = *(const s16x8*)&Qh[(size_t)(q0 + l31) * HD + kb * 16 + hi * 8];

  f32x16 acc0 = {}, acc1 = {};
  float m_ = -1e30f, l_ = 0.f;

  auto STAGE = [&](int kt_, int buf_) {
#pragma unroll
    for (int c = 0; c < 2; c++) {
      const int row = c * 32 + (tid >> 3);
      const int colb = ((tid & 7) * 16) ^ ((row & 7) << 4);
      __builtin_amdgcn_global_load_lds(
          (GBuf*)((const char*)Kh + ((size_t)(kt_ * 64 + row) * HD) * 2 + colb),
          (LBuf*)((char*)&KsS[buf_][0] + c * 4096 + tid * 16), 16, 0, 0);
      __builtin_amdgcn_global_load_lds(
          (GBuf*)((const char*)Vh + ((size_t)row * SEQ + kt_ * 64) * 2 + colb),
          (LBuf*)((char*)&VtS[buf_][0] + c * 4096 + tid * 16), 16, 0, 0);
    }
  };

  const int NT = SEQ / 64;  // 32
  STAGE(0, 0);
  STAGE(1, 1);

  for (int kt = 0; kt < NT; kt++) {
    const int cur = kt % 3;
    // tile kt's 4 loads are the oldest outstanding; leave the next tile's
    // 4 in flight across the barrier (T4 counted-vmcnt). Tail: full drain.
    if (kt < NT - 1) {
      asm volatile("s_waitcnt vmcnt(4)" ::: "memory");
    } else {
      asm volatile("s_waitcnt vmcnt(0)" ::: "memory");
    }
    __builtin_amdgcn_sched_barrier(0);
    __builtin_amdgcn_s_barrier();  // all waves' tile-kt loads now in LDS
    if (kt + 2 < NT) STAGE(kt + 2, (kt + 2) % 3);  // overwrites buf read at kt-1

    // ---- S^T = K . Q^T
    f32x16 s0 = {}, s1 = {};
    __builtin_amdgcn_s_setprio(1);
#pragma unroll
    for (int kb = 0; kb < 4; kb++) {
      const int coff = ((kb * 2 + hi) ^ rswz) << 4;
      const s16x8 ak0 = *(const s16x8*)((const char*)&KsS[cur][0] + l31 * 128 + coff);
      const s16x8 ak1 = *(const s16x8*)((const char*)&KsS[cur][0] + (32 + l31) * 128 + coff);
      s0 = __builtin_amdgcn_mfma_f32_32x32x16_bf16(ak0, aq[kb], s0, 0, 0, 0);
      s1 = __builtin_amdgcn_mfma_f32_32x32x16_bf16(ak1, aq[kb], s1, 0, 0, 0);
    }
    __builtin_amdgcn_s_setprio(0);

    // ---- online softmax (q lane-local)
    float t8[8];
#pragma unroll
    for (int i = 0; i < 8; i++)
      t8[i] = fmaxf(fmaxf(s0[i], s0[i + 8]), fmaxf(s1[i], s1[i + 8]));
    float tm = fmaxf(fmaxf(fmaxf(t8[0], t8[1]), fmaxf(t8[2], t8[3])),
                     fmaxf(fmaxf(t8[4], t8[5]), fmaxf(t8[6], t8[7])));
    tm = fmaxf(tm, __shfl_xor(tm, 32));

    if (!__all(tm - m_ <= 8.0f)) {  // defer-max
      const float mnew = fmaxf(m_, tm);
      const float fs = exp2f(m_ - mnew);
      m_ = mnew;
      l_ *= fs;
#pragma unroll
      for (int r = 0; r < 16; r++) { acc0[r] *= fs; acc1[r] *= fs; }
    }

#pragma unroll
    for (int r = 0; r < 16; r++) {
      s0[r] = exp2f(s0[r] - m_);
      s1[r] = exp2f(s1[r] - m_);
    }
    float sa[8];
#pragma unroll
    for (int i = 0; i < 8; i++) sa[i] = (s0[i] + s0[i + 8]) + (s1[i] + s1[i + 8]);
    float sum = ((sa[0] + sa[1]) + (sa[2] + sa[3])) + ((sa[4] + sa[5]) + (sa[6] + sa[7]));
    sum += __shfl_xor(sum, 32);
    l_ += sum;

    // ---- P fragments in registers
    s16x8 pa[4];
    pa[0] = pack_pfrag(s0[0], s0[1], s0[2], s0[3], s0[4], s0[5], s0[6], s0[7]);
    pa[1] = pack_pfrag(s0[8], s0[9], s0[10], s0[11], s0[12], s0[13], s0[14], s0[15]);
    pa[2] = pack_pfrag(s1[0], s1[1], s1[2], s1[3], s1[4], s1[5], s1[6], s1[7]);
    pa[3] = pack_pfrag(s1[8], s1[9], s1[10], s1[11], s1[12], s1[13], s1[14], s1[15]);

    // ---- O^T += V^T . P^T
    __builtin_amdgcn_s_setprio(1);
#pragma unroll
    for (int kp = 0; kp < 4; kp++) {
      const int coff = ((kp * 2 + hi) ^ rswz) << 4;
      const s16x8 av0 = *(const s16x8*)((const char*)&VtS[cur][0] + l31 * 128 + coff);
      const s16x8 av1 = *(const s16x8*)((const char*)&VtS[cur][0] + (32 + l31) * 128 + coff);
      acc0 = __builtin_amdgcn_mfma_f32_32x32x16_bf16(av0, pa[kp], acc0, 0, 0, 0);
      acc1 = __builtin_amdgcn_mfma_f32_32x32x16_bf16(av1, pa[kp], acc1, 0, 0, 0);
    }
    __builtin_amdgcn_s_setprio(0);
  }

  // ---- epilogue
  const float inv = 1.0f / l_;
  const int b = bh / NH, h = bh % NH;
  const int n = q0 + l31;
  __hip_bfloat16* dst = &CTX[((size_t)(b * SEQ + n)) * ED + h * HD];
#pragma unroll
  for (int g = 0; g < 4; g++) {
    union { s16x4 v; __hip_bfloat16 hh[4]; } p0, p1;
#pragma unroll
    for (int r = 0; r < 4; r++) {
      p0.hh[r] = __float2bfloat16(acc0[4 * g + r] * inv);
      p1.hh[r] = __float2bfloat16(acc1[4 * g + r] * inv);
    }
    *(s16x4*)&dst[8 * g + 4 * hi] = p0.v;
    *(s16x4*)&dst[32 + 8 * g + 4 * hi] = p1.v;
  }
}

// ---------------------------------------------------------------------------
extern "C" void kernel_launch(void* const* d_in, const int* in_sizes, int n_in,
                              void* d_out, int out_size, void* d_ws, size_t ws_size,
                              hipStream_t stream) {
  const float* x = (const float*)d_in[0];
  const float* wq = (const float*)d_in[1];
  const float* bq = (const float*)d_in[2];
  const float* wk = (const float*)d_in[3];
  const float* bk = (const float*)d_in[4];
  const float* wv = (const float*)d_in[5];
  const float* bv = (const float*)d_in[6];
  const float* wo = (const float*)d_in[7];
  const float* bo = (const float*)d_in[8];
  float* out = (float*)d_out;

  const int BN = in_sizes[0] / ED;  // 4096

  char* w = (char*)d_ws;
  __hip_bfloat16* xbf = (__hip_bfloat16*)(w);
  __hip_bfloat16* wqb = (__hip_bfloat16*)(w + (8 << 20));
  __hip_bfloat16* wkb = (__hip_bfloat16*)(w + (10 << 20));
  __hip_bfloat16* wvb = (__hip_bfloat16*)(w + (12 << 20));
  __hip_bfloat16* wob = (__hip_bfloat16*)(w + (14 << 20));
  __hip_bfloat16* Qb = (__hip_bfloat16*)(w + (16 << 20));
  __hip_bfloat16* Kb = (__hip_bfloat16*)(w + (24 << 20));
  __hip_bfloat16* VTb = (__hip_bfloat16*)(w + (32 << 20));
  __hip_bfloat16* CTXb = (__hip_bfloat16*)(w + (40 << 20));

  cvt5<<<1024, 256, 0, stream>>>(x, wq, wk, wv, wo, xbf, wqb, wkb, wvb, wob,
                                 BN * ED, ED * ED, ED * ED, ED * ED, ED * ED);

  const dim3 blk(256);
  gemm_qkv<<<dim3(ED / 128, BN / 128, 3), blk, 0, stream>>>(
      xbf, wqb, bq, wkb, bk, wvb, bv, Qb, Kb, VTb);

  attn_bf16<<<dim3(512), blk, 0, stream>>>(Qb, Kb, VTb, CTXb);

  gemm_out<<<dim3(ED / 128, BN / 128), blk, 0, stream>>>(CTXb, wob, bo, out);
}

// Round 10
// 237.366 us; speedup vs baseline: 6.4451x; 1.0016x over previous
//
#include <hip/hip_runtime.h>
#include <hip/hip_bf16.h>

#define ED 1024
#define NH 16
#define HD 64
#define SEQ 2048

typedef float f32x4 __attribute__((ext_vector_type(4)));
typedef float f32x16 __attribute__((ext_vector_type(16)));
typedef short s16x8 __attribute__((ext_vector_type(8)));
typedef short s16x4 __attribute__((ext_vector_type(4)));
typedef __attribute__((address_space(1))) const unsigned int GBuf;
typedef __attribute__((address_space(3))) unsigned int LBuf;

#define QSC 0.18033688011112042f  // 0.125 * log2(e): fold softmax scale + exp2 base

union BF8 { s16x8 v; __hip_bfloat16 h[8]; };

__device__ __forceinline__ unsigned cvt_pk_bf16(float lo, float hi) {
  unsigned r;
  asm("v_cvt_pk_bf16_f32 %0, %1, %2" : "=v"(r) : "v"(lo), "v"(hi));
  return r;
}

// Build one PV fragment (8 bf16, K=16) from this lane's 8 f32 P values.
__device__ __forceinline__ s16x8 pack_pfrag(float p0, float p1, float p2, float p3,
                                            float p4, float p5, float p6, float p7) {
  unsigned w0 = cvt_pk_bf16(p0, p1), w1 = cvt_pk_bf16(p2, p3);
  unsigned w2 = cvt_pk_bf16(p4, p5), w3 = cvt_pk_bf16(p6, p7);
  asm("v_permlane32_swap_b32 %0, %1" : "+v"(w0), "+v"(w2));
  asm("v_permlane32_swap_b32 %0, %1" : "+v"(w1), "+v"(w3));
  union { unsigned u[4]; s16x8 v; } r;
  r.u[0] = w0; r.u[1] = w1; r.u[2] = w2; r.u[3] = w3;
  return r.v;
}

// ---------------------------------------------------------------------------
// fp32 -> bf16 conversion
// ---------------------------------------------------------------------------
__device__ inline void cvt_one(const float* __restrict__ s, __hip_bfloat16* __restrict__ d,
                               int n, int t, int stride) {
  const int n8 = n >> 3;
  for (int i = t; i < n8; i += stride) {
    const float4 u = ((const float4*)s)[2 * i];
    const float4 v = ((const float4*)s)[2 * i + 1];
    BF8 o;
    o.h[0] = __float2bfloat16(u.x); o.h[1] = __float2bfloat16(u.y);
    o.h[2] = __float2bfloat16(u.z); o.h[3] = __float2bfloat16(u.w);
    o.h[4] = __float2bfloat16(v.x); o.h[5] = __float2bfloat16(v.y);
    o.h[6] = __float2bfloat16(v.z); o.h[7] = __float2bfloat16(v.w);
    ((s16x8*)d)[i] = o.v;
  }
}

__global__ __launch_bounds__(256) void cvt5(const float* s0, const float* s1, const float* s2,
                                            const float* s3, const float* s4,
                                            __hip_bfloat16* d0, __hip_bfloat16* d1,
                                            __hip_bfloat16* d2, __hip_bfloat16* d3,
                                            __hip_bfloat16* d4,
                                            int n0, int n1, int n2, int n3, int n4) {
  const int stride = gridDim.x * blockDim.x;
  const int t = blockIdx.x * blockDim.x + threadIdx.x;
  cvt_one(s0, d0, n0, t, stride);
  cvt_one(s1, d1, n1, t, stride);
  cvt_one(s2, d2, n2, t, stride);
  cvt_one(s3, d3, n3, t, stride);
  cvt_one(s4, d4, n4, t, stride);
}

// ---------------------------------------------------------------------------
// Fused QKV GEMM: 256x256 tile, BK=32, 8 waves (512 thr), 2-phase dbuf.
// Wave owns 128x64 output (2M x 4N wave grid), acc[8][4].
// z<2 : out bf16 [B*NH][SEQ][HD], (acc+bias)*scale (Q: QSC)
// z==2: out bf16 V^T [B*NH][HD][SEQ], packed 4-contiguous stores
// ---------------------------------------------------------------------------
__global__ __launch_bounds__(512) void gemm_qkv(const __hip_bfloat16* __restrict__ A,
                                                const __hip_bfloat16* __restrict__ wq,
                                                const float* __restrict__ bq,
                                                const __hip_bfloat16* __restrict__ wk,
                                                const float* __restrict__ bk,
                                                const __hip_bfloat16* __restrict__ wv,
                                                const float* __restrict__ bv,
                                                __hip_bfloat16* __restrict__ Qo,
                                                __hip_bfloat16* __restrict__ Ko,
                                                __hip_bfloat16* __restrict__ Vo) {
  __shared__ __hip_bfloat16 As[2][256 * 32];
  __shared__ __hip_bfloat16 Bs[2][256 * 32];  // 64 KB total

  // bijective XCD chunk swizzle: 192 blocks, 24 consecutive works per XCD
  const int lin = blockIdx.x;
  const int work = (lin & 7) * 24 + (lin >> 3);
  const int z = work >> 6;
  const int rem = work & 63;
  const int m0 = (rem >> 2) * 256, n0 = (rem & 3) * 256;

  const __hip_bfloat16* W = (z == 0) ? wq : (z == 1) ? wk : wv;
  const float* bias = (z == 0) ? bq : (z == 1) ? bk : bv;

  const int tid = threadIdx.x;
  const int wave = tid >> 6, lane = tid & 63;
  const int ln15 = lane & 15, lg = lane >> 4;
  const int wr = (wave >> 2) * 128, wc = (wave & 3) * 64;

  f32x4 acc[8][4];
#pragma unroll
  for (int i = 0; i < 8; i++)
#pragma unroll
    for (int j = 0; j < 4; j++) acc[i][j] = (f32x4){0.f, 0.f, 0.f, 0.f};

  const int srow = tid >> 2;          // 0..127 row per pass
  const int sk = (tid & 3) * 8;       // k offset (8 bf16 = 16 B)

  auto STAGE = [&](int t, int buf) {
    const int k0 = t * 32;
#pragma unroll
    for (int c = 0; c < 2; c++) {
      const int r = c * 128 + srow;
      __builtin_amdgcn_global_load_lds((GBuf*)(A + (size_t)(m0 + r) * ED + k0 + sk),
                                       (LBuf*)((char*)&As[buf][0] + c * 8192 + tid * 16), 16, 0, 0);
      __builtin_amdgcn_global_load_lds((GBuf*)(W + (size_t)(n0 + r) * ED + k0 + sk),
                                       (LBuf*)((char*)&Bs[buf][0] + c * 8192 + tid * 16), 16, 0, 0);
    }
  };

  const int NT = ED / 32;  // 32
  STAGE(0, 0);
  __syncthreads();
  for (int t = 0; t < NT; t++) {
    const int cur = t & 1;
    if (t + 1 < NT) STAGE(t + 1, cur ^ 1);  // flies under compute, drained at barrier
    __builtin_amdgcn_s_setprio(1);
    s16x8 a[8], b[4];
#pragma unroll
    for (int i = 0; i < 8; i++)
      a[i] = *(const s16x8*)&As[cur][(wr + i * 16 + ln15) * 32 + lg * 8];
#pragma unroll
    for (int j = 0; j < 4; j++)
      b[j] = *(const s16x8*)&Bs[cur][(wc + j * 16 + ln15) * 32 + lg * 8];
#pragma unroll
    for (int i = 0; i < 8; i++)
#pragma unroll
      for (int j = 0; j < 4; j++)
        acc[i][j] = __builtin_amdgcn_mfma_f32_16x16x32_bf16(a[i], b[j], acc[i][j], 0, 0, 0);
    __builtin_amdgcn_s_setprio(0);
    __syncthreads();
  }

  const float scale = (z == 0) ? QSC : 1.0f;
  if (z < 2) {
    __hip_bfloat16* out = (z == 0) ? Qo : Ko;
#pragma unroll
    for (int j = 0; j < 4; j++) {
      const int e = n0 + wc + j * 16 + ln15;
      const float bvv = bias[e];
      const int h = e >> 6, hd = e & 63;
#pragma unroll
      for (int i = 0; i < 8; i++) {
#pragma unroll
        for (int r = 0; r < 4; r++) {
          const int m = m0 + wr + i * 16 + lg * 4 + r;
          const int b = m >> 11, n = m & 2047;
          out[(((size_t)(b * NH + h)) * SEQ + n) * HD + hd] =
              __float2bfloat16((acc[i][j][r] + bvv) * scale);
        }
      }
    }
  } else {
#pragma unroll
    for (int j = 0; j < 4; j++) {
      const int e = n0 + wc + j * 16 + ln15;
      const float bvv = bias[e];
      const int h = e >> 6, hd = e & 63;
#pragma unroll
      for (int i = 0; i < 8; i++) {
        const int m = m0 + wr + i * 16 + lg * 4;
        const int b = m >> 11, n = m & 2047;
        union { s16x4 v; __hip_bfloat16 hh[4]; } pk;
#pragma unroll
        for (int r = 0; r < 4; r++) pk.hh[r] = __float2bfloat16(acc[i][j][r] + bvv);
        *(s16x4*)&Vo[(((size_t)(b * NH + h)) * HD + hd) * SEQ + n] = pk.v;
      }
    }
  }
}

// ---------------------------------------------------------------------------
// Output GEMM: same 256x256/BK=32 structure, fp32 out [M][ED]
// ---------------------------------------------------------------------------
__global__ __launch_bounds__(512) void gemm_out(const __hip_bfloat16* __restrict__ A,
                                                const __hip_bfloat16* __restrict__ W,
                                                const float* __restrict__ bias,
                                                float* __restrict__ out) {
  __shared__ __hip_bfloat16 As[2][256 * 32];
  __shared__ __hip_bfloat16 Bs[2][256 * 32];

  const int lin = blockIdx.x;                 // 64 blocks, 8 works/XCD
  const int work = (lin & 7) * 8 + (lin >> 3);
  const int m0 = (work >> 2) * 256, n0 = (work & 3) * 256;

  const int tid = threadIdx.x;
  const int wave = tid >> 6, lane = tid & 63;
  const int ln15 = lane & 15, lg = lane >> 4;
  const int wr = (wave >> 2) * 128, wc = (wave & 3) * 64;

  f32x4 acc[8][4];
#pragma unroll
  for (int i = 0; i < 8; i++)
#pragma unroll
    for (int j = 0; j < 4; j++) acc[i][j] = (f32x4){0.f, 0.f, 0.f, 0.f};

  const int srow = tid >> 2;
  const int sk = (tid & 3) * 8;

  auto STAGE = [&](int t, int buf) {
    const int k0 = t * 32;
#pragma unroll
    for (int c = 0; c < 2; c++) {
      const int r = c * 128 + srow;
      __builtin_amdgcn_global_load_lds((GBuf*)(A + (size_t)(m0 + r) * ED + k0 + sk),
                                       (LBuf*)((char*)&As[buf][0] + c * 8192 + tid * 16), 16, 0, 0);
      __builtin_amdgcn_global_load_lds((GBuf*)(W + (size_t)(n0 + r) * ED + k0 + sk),
                                       (LBuf*)((char*)&Bs[buf][0] + c * 8192 + tid * 16), 16, 0, 0);
    }
  };

  const int NT = ED / 32;
  STAGE(0, 0);
  __syncthreads();
  for (int t = 0; t < NT; t++) {
    const int cur = t & 1;
    if (t + 1 < NT) STAGE(t + 1, cur ^ 1);
    __builtin_amdgcn_s_setprio(1);
    s16x8 a[8], b[4];
#pragma unroll
    for (int i = 0; i < 8; i++)
      a[i] = *(const s16x8*)&As[cur][(wr + i * 16 + ln15) * 32 + lg * 8];
#pragma unroll
    for (int j = 0; j < 4; j++)
      b[j] = *(const s16x8*)&Bs[cur][(wc + j * 16 + ln15) * 32 + lg * 8];
#pragma unroll
    for (int i = 0; i < 8; i++)
#pragma unroll
      for (int j = 0; j < 4; j++)
        acc[i][j] = __builtin_amdgcn_mfma_f32_16x16x32_bf16(a[i], b[j], acc[i][j], 0, 0, 0);
    __builtin_amdgcn_s_setprio(0);
    __syncthreads();
  }

#pragma unroll
  for (int j = 0; j < 4; j++) {
    const int e = n0 + wc + j * 16 + ln15;
    const float bvv = bias[e];
#pragma unroll
    for (int i = 0; i < 8; i++)
#pragma unroll
      for (int r = 0; r < 4; r++) {
        const int m = m0 + wr + i * 16 + lg * 4 + r;
        out[(size_t)m * ED + e] = acc[i][j][r] + bvv;
      }
  }
}

// ---------------------------------------------------------------------------
// Flash attention v5: split-KV 8-wave. Waves 0-3 (parity 0) process even KV
// tiles, waves 4-7 odd; same 128 q rows. Per-parity 2-buffer staging
// (round-5 structure). Final merge of the two online-softmax states via LDS.
// 32x32x16 MFMA; in-register P (cvt_pk+permlane32_swap); defer-max THR=8.
// ---------------------------------------------------------------------------
__global__ __launch_bounds__(512, 4) void attn_bf16(const __hip_bfloat16* __restrict__ Q,
                                                    const __hip_bfloat16* __restrict__ K,
                                                    const __hip_bfloat16* __restrict__ VT,
                                                    __hip_bfloat16* __restrict__ CTX) {
  // 64 KB raw LDS: staging [parity][buf][K/V][8KB], reused for the merge.
  __shared__ char ldsraw[65536];
  float* mgacc = (float*)ldsraw;                       // [4][32][66]
  float* mgml = (float*)(ldsraw + 4 * 32 * 66 * 4);    // [4][2][32]

  const int tid = threadIdx.x;
  const int wave = tid >> 6, lane = tid & 63;
  const int l31 = lane & 31, hi = lane >> 5;
  const int rswz = l31 & 7;
  const int par = wave >> 2;   // KV parity group
  const int wq = wave & 3;     // q-group

  // XCD swizzle: a head's 16 q-blocks share one XCD's L2
  const int bid = blockIdx.x;
  const int work = (bid & 7) * 64 + (bid >> 3);
  const int qb = work & 15;
  const int bh = work >> 4;

  const __hip_bfloat16* Qh = Q + (size_t)bh * SEQ * HD;
  const __hip_bfloat16* Kh = K + (size_t)bh * SEQ * HD;
  const __hip_bfloat16* Vh = VT + (size_t)bh * HD * SEQ;

  const int q0 = qb * 128 + wq * 32;

  s16x8 aq[4];
#pragma unroll
  for (int kb = 0; kb < 4; kb++)
    aq[kb] = *(const s16x8*)&Qh[(size_t)(q0 + l31) * HD + kb * 16 + hi * 8];

  f32x16 acc0 = {}, acc1 = {};
  float m_ = -1e30f, l_ = 0.f;

  const int lt = tid & 255;
  auto STAGE = [&](int tile, int buf) {
#pragma unroll
    for (int c = 0; c < 2; c++) {
      const int row = c * 32 + (lt >> 3);
      const int colb = ((lt & 7) * 16) ^ ((row & 7) << 4);
      char* kbase = ldsraw + ((par * 2 + buf) * 2 + 0) * 8192;
      char* vbase = ldsraw + ((par * 2 + buf) * 2 + 1) * 8192;
      __builtin_amdgcn_global_load_lds(
          (GBuf*)((const char*)Kh + ((size_t)(tile * 64 + row) * HD) * 2 + colb),
          (LBuf*)(kbase + c * 4096 + lt * 16), 16, 0, 0);
      __builtin_amdgcn_global_load_lds(
          (GBuf*)((const char*)Vh + ((size_t)row * SEQ + tile * 64) * 2 + colb),
          (LBuf*)(vbase + c * 4096 + lt * 16), 16, 0, 0);
    }
  };

  const int NI = SEQ / 128;  // 16 iterations per parity group
  STAGE(par, 0);
  for (int i = 0; i < NI; i++) {
    const int cur = i & 1;
    __syncthreads();  // drains vmcnt -> buf[cur] staged; prev reads of cur^1 done
    if (i + 1 < NI) STAGE(2 * (i + 1) + par, cur ^ 1);

    const char* Ksb = ldsraw + ((par * 2 + cur) * 2 + 0) * 8192;
    const char* Vtb = ldsraw + ((par * 2 + cur) * 2 + 1) * 8192;

    // ---- S^T = K . Q^T
    f32x16 s0 = {}, s1 = {};
    __builtin_amdgcn_s_setprio(1);
#pragma unroll
    for (int kb = 0; kb < 4; kb++) {
      const int coff = ((kb * 2 + hi) ^ rswz) << 4;
      const s16x8 ak0 = *(const s16x8*)(Ksb + l31 * 128 + coff);
      const s16x8 ak1 = *(const s16x8*)(Ksb + (32 + l31) * 128 + coff);
      s0 = __builtin_amdgcn_mfma_f32_32x32x16_bf16(ak0, aq[kb], s0, 0, 0, 0);
      s1 = __builtin_amdgcn_mfma_f32_32x32x16_bf16(ak1, aq[kb], s1, 0, 0, 0);
    }
    __builtin_amdgcn_s_setprio(0);

    // ---- online softmax (q lane-local)
    float t8[8];
#pragma unroll
    for (int i2 = 0; i2 < 8; i2++)
      t8[i2] = fmaxf(fmaxf(s0[i2], s0[i2 + 8]), fmaxf(s1[i2], s1[i2 + 8]));
    float tm = fmaxf(fmaxf(fmaxf(t8[0], t8[1]), fmaxf(t8[2], t8[3])),
                     fmaxf(fmaxf(t8[4], t8[5]), fmaxf(t8[6], t8[7])));
    tm = fmaxf(tm, __shfl_xor(tm, 32));

    if (!__all(tm - m_ <= 8.0f)) {  // defer-max
      const float mnew = fmaxf(m_, tm);
      const float fs = exp2f(m_ - mnew);
      m_ = mnew;
      l_ *= fs;
#pragma unroll
      for (int r = 0; r < 16; r++) { acc0[r] *= fs; acc1[r] *= fs; }
    }

#pragma unroll
    for (int r = 0; r < 16; r++) {
      s0[r] = exp2f(s0[r] - m_);
      s1[r] = exp2f(s1[r] - m_);
    }
    float sa[8];
#pragma unroll
    for (int i2 = 0; i2 < 8; i2++) sa[i2] = (s0[i2] + s0[i2 + 8]) + (s1[i2] + s1[i2 + 8]);
    float sum = ((sa[0] + sa[1]) + (sa[2] + sa[3])) + ((sa[4] + sa[5]) + (sa[6] + sa[7]));
    sum += __shfl_xor(sum, 32);
    l_ += sum;

    // ---- P fragments in registers
    s16x8 pa[4];
    pa[0] = pack_pfrag(s0[0], s0[1], s0[2], s0[3], s0[4], s0[5], s0[6], s0[7]);
    pa[1] = pack_pfrag(s0[8], s0[9], s0[10], s0[11], s0[12], s0[13], s0[14], s0[15]);
    pa[2] = pack_pfrag(s1[0], s1[1], s1[2], s1[3], s1[4], s1[5], s1[6], s1[7]);
    pa[3] = pack_pfrag(s1[8], s1[9], s1[10], s1[11], s1[12], s1[13], s1[14], s1[15]);

    // ---- O^T += V^T . P^T
    __builtin_amdgcn_s_setprio(1);
#pragma unroll
    for (int kp = 0; kp < 4; kp++) {
      const int coff = ((kp * 2 + hi) ^ rswz) << 4;
      const s16x8 av0 = *(const s16x8*)(Vtb + l31 * 128 + coff);
      const s16x8 av1 = *(const s16x8*)(Vtb + (32 + l31) * 128 + coff);
      acc0 = __builtin_amdgcn_mfma_f32_32x32x16_bf16(av0, pa[kp], acc0, 0, 0, 0);
      acc1 = __builtin_amdgcn_mfma_f32_32x32x16_bf16(av1, pa[kp], acc1, 0, 0, 0);
    }
    __builtin_amdgcn_s_setprio(0);
  }

  // ---- merge the two parity states (upper waves publish, lower waves combine)
  __syncthreads();  // all reads of staging LDS done; safe to reuse as merge area
  if (wave >= 4) {
    const int w = wave - 4;
    float* ap = &mgacc[(w * 32 + l31) * 66];
#pragma unroll
    for (int g = 0; g < 4; g++)
#pragma unroll
      for (int r = 0; r < 4; r++) {
        ap[8 * g + 4 * hi + r] = acc0[4 * g + r];
        ap[32 + 8 * g + 4 * hi + r] = acc1[4 * g + r];
      }
    if (hi == 0) {
      mgml[(w * 2 + 0) * 32 + l31] = m_;
      mgml[(w * 2 + 1) * 32 + l31] = l_;
    }
  }
  __syncthreads();
  if (wave < 4) {
    const float m1 = mgml[(wave * 2 + 0) * 32 + l31];
    const float l1 = mgml[(wave * 2 + 1) * 32 + l31];
    const float mm = fmaxf(m_, m1);
    const float f0 = exp2f(m_ - mm), f1 = exp2f(m1 - mm);
    const float inv = 1.0f / (l_ * f0 + l1 * f1);
    const float* ap = &mgacc[(wave * 32 + l31) * 66];

    const int b = bh / NH, h = bh % NH;
    const int n = q0 + l31;
    __hip_bfloat16* dst = &CTX[((size_t)(b * SEQ + n)) * ED + h * HD];
#pragma unroll
    for (int g = 0; g < 4; g++) {
      union { s16x4 v; __hip_bfloat16 hh[4]; } p0, p1;
#pragma unroll
      for (int r = 0; r < 4; r++) {
        const float o0 = (acc0[4 * g + r] * f0 + ap[8 * g + 4 * hi + r] * f1) * inv;
        const float o1 = (acc1[4 * g + r] * f0 + ap[32 + 8 * g + 4 * hi + r] * f1) * inv;
        p0.hh[r] = __float2bfloat16(o0);
        p1.hh[r] = __float2bfloat16(o1);
      }
      *(s16x4*)&dst[8 * g + 4 * hi] = p0.v;
      *(s16x4*)&dst[32 + 8 * g + 4 * hi] = p1.v;
    }
  }
}

// ---------------------------------------------------------------------------
extern "C" void kernel_launch(void* const* d_in, const int* in_sizes, int n_in,
                              void* d_out, int out_size, void* d_ws, size_t ws_size,
                              hipStream_t stream) {
  const float* x = (const float*)d_in[0];
  const float* wq = (const float*)d_in[1];
  const float* bq = (const float*)d_in[2];
  const float* wk = (const float*)d_in[3];
  const float* bk = (const float*)d_in[4];
  const float* wv = (const float*)d_in[5];
  const float* bv = (const float*)d_in[6];
  const float* wo = (const float*)d_in[7];
  const float* bo = (const float*)d_in[8];
  float* out = (float*)d_out;

  const int BN = in_sizes[0] / ED;  // 4096

  char* w = (char*)d_ws;
  __hip_bfloat16* xbf = (__hip_bfloat16*)(w);
  __hip_bfloat16* wqb = (__hip_bfloat16*)(w + (8 << 20));
  __hip_bfloat16* wkb = (__hip_bfloat16*)(w + (10 << 20));
  __hip_bfloat16* wvb = (__hip_bfloat16*)(w + (12 << 20));
  __hip_bfloat16* wob = (__hip_bfloat16*)(w + (14 << 20));
  __hip_bfloat16* Qb = (__hip_bfloat16*)(w + (16 << 20));
  __hip_bfloat16* Kb = (__hip_bfloat16*)(w + (24 << 20));
  __hip_bfloat16* VTb = (__hip_bfloat16*)(w + (32 << 20));
  __hip_bfloat16* CTXb = (__hip_bfloat16*)(w + (40 << 20));

  cvt5<<<1024, 256, 0, stream>>>(x, wq, wk, wv, wo, xbf, wqb, wkb, wvb, wob,
                                 BN * ED, ED * ED, ED * ED, ED * ED, ED * ED);

  gemm_qkv<<<dim3(192), dim3(512), 0, stream>>>(
      xbf, wqb, bq, wkb, bk, wvb, bv, Qb, Kb, VTb);

  attn_bf16<<<dim3(512), dim3(512), 0, stream>>>(Qb, Kb, VTb, CTXb);

  gemm_out<<<dim3(64), dim3(512), 0, stream>>>(CTXb, wob, bo, out);
}

// Round 13
// 219.181 us; speedup vs baseline: 6.9799x; 1.0830x over previous
//
#include <hip/hip_runtime.h>
#include <hip/hip_bf16.h>

#define ED 1024
#define NH 16
#define HD 64
#define SEQ 2048

typedef float f32x4 __attribute__((ext_vector_type(4)));
typedef float f32x16 __attribute__((ext_vector_type(16)));
typedef short s16x8 __attribute__((ext_vector_type(8)));
typedef short s16x4 __attribute__((ext_vector_type(4)));
typedef __attribute__((address_space(1))) const unsigned int GBuf;
typedef __attribute__((address_space(3))) unsigned int LBuf;

#define QSC 0.18033688011112042f  // 0.125 * log2(e): fold softmax scale + exp2 base

union BF8 { s16x8 v; __hip_bfloat16 h[8]; };

__device__ __forceinline__ unsigned cvt_pk_bf16(float lo, float hi) {
  unsigned r;
  asm("v_cvt_pk_bf16_f32 %0, %1, %2" : "=v"(r) : "v"(lo), "v"(hi));
  return r;
}

// Build one PV fragment (8 bf16, K=16) from this lane's 8 f32 P values.
__device__ __forceinline__ s16x8 pack_pfrag(float p0, float p1, float p2, float p3,
                                            float p4, float p5, float p6, float p7) {
  unsigned w0 = cvt_pk_bf16(p0, p1), w1 = cvt_pk_bf16(p2, p3);
  unsigned w2 = cvt_pk_bf16(p4, p5), w3 = cvt_pk_bf16(p6, p7);
  asm("v_permlane32_swap_b32 %0, %1" : "+v"(w0), "+v"(w2));
  asm("v_permlane32_swap_b32 %0, %1" : "+v"(w1), "+v"(w3));
  union { unsigned u[4]; s16x8 v; } r;
  r.u[0] = w0; r.u[1] = w1; r.u[2] = w2; r.u[3] = w3;
  return r.v;
}

// ---------------------------------------------------------------------------
// fp32 -> bf16 conversion
// ---------------------------------------------------------------------------
__device__ inline void cvt_one(const float* __restrict__ s, __hip_bfloat16* __restrict__ d,
                               int n, int t, int stride) {
  const int n8 = n >> 3;
  for (int i = t; i < n8; i += stride) {
    const float4 u = ((const float4*)s)[2 * i];
    const float4 v = ((const float4*)s)[2 * i + 1];
    BF8 o;
    o.h[0] = __float2bfloat16(u.x); o.h[1] = __float2bfloat16(u.y);
    o.h[2] = __float2bfloat16(u.z); o.h[3] = __float2bfloat16(u.w);
    o.h[4] = __float2bfloat16(v.x); o.h[5] = __float2bfloat16(v.y);
    o.h[6] = __float2bfloat16(v.z); o.h[7] = __float2bfloat16(v.w);
    ((s16x8*)d)[i] = o.v;
  }
}

__global__ __launch_bounds__(256) void cvt5(const float* s0, const float* s1, const float* s2,
                                            const float* s3, const float* s4,
                                            __hip_bfloat16* d0, __hip_bfloat16* d1,
                                            __hip_bfloat16* d2, __hip_bfloat16* d3,
                                            __hip_bfloat16* d4,
                                            int n0, int n1, int n2, int n3, int n4) {
  const int stride = gridDim.x * blockDim.x;
  const int t = blockIdx.x * blockDim.x + threadIdx.x;
  cvt_one(s0, d0, n0, t, stride);
  cvt_one(s1, d1, n1, t, stride);
  cvt_one(s2, d2, n2, t, stride);
  cvt_one(s3, d3, n3, t, stride);
  cvt_one(s4, d4, n4, t, stride);
}

// ---------------------------------------------------------------------------
// Fused QKV GEMM: 128x128 tile, BK=64, 4 waves, 2-phase dbuf (round-6 K-loop,
// 768 blocks = full GPU). z<2 (Q,K): SWAPPED-operand MFMA -> C^T layout
// (lane holds 4 consecutive e) -> packed s16x4 stores along hd.
// z==2 (V): normal orientation -> V^T [B*NH][HD][SEQ], packed along n.
// ---------------------------------------------------------------------------
__global__ __launch_bounds__(256) void gemm_qkv(const __hip_bfloat16* __restrict__ A,
                                                const __hip_bfloat16* __restrict__ wq,
                                                const float* __restrict__ bq,
                                                const __hip_bfloat16* __restrict__ wk,
                                                const float* __restrict__ bk,
                                                const __hip_bfloat16* __restrict__ wv,
                                                const float* __restrict__ bv,
                                                __hip_bfloat16* __restrict__ Qo,
                                                __hip_bfloat16* __restrict__ Ko,
                                                __hip_bfloat16* __restrict__ Vo) {
  __shared__ __hip_bfloat16 As[2][128 * 64];
  __shared__ __hip_bfloat16 Bs[2][128 * 64];

  // XCD chunk swizzle: 768 blocks -> each XCD owns 96 consecutive work ids
  const int lin = (blockIdx.z * 32 + blockIdx.y) * 8 + blockIdx.x;
  const int work = (lin & 7) * 96 + (lin >> 3);
  const int z = work >> 8;
  const int rem = work & 255;
  const int m0 = (rem >> 3) * 128, n0 = (rem & 7) * 128;

  const __hip_bfloat16* W = (z == 0) ? wq : (z == 1) ? wk : wv;
  const float* bias = (z == 0) ? bq : (z == 1) ? bk : bv;

  const int tid = threadIdx.x;
  const int wave = tid >> 6, lane = tid & 63;
  const int ln15 = lane & 15, lg = lane >> 4;
  const int wr = (wave >> 1) * 64, wc = (wave & 1) * 64;

  f32x4 acc[4][4];
#pragma unroll
  for (int i = 0; i < 4; i++)
#pragma unroll
    for (int j = 0; j < 4; j++) acc[i][j] = (f32x4){0.f, 0.f, 0.f, 0.f};

  const int srow = tid >> 3;
  const int sk = (tid & 7) * 8;

  auto STAGE = [&](int t, int buf) {
    const int k0 = t * 64;
#pragma unroll
    for (int c = 0; c < 4; c++) {
      const int r = c * 32 + srow;
      __builtin_amdgcn_global_load_lds((GBuf*)(A + (size_t)(m0 + r) * ED + k0 + sk),
                                       (LBuf*)((char*)&As[buf][0] + c * 4096 + tid * 16), 16, 0, 0);
      __builtin_amdgcn_global_load_lds((GBuf*)(W + (size_t)(n0 + r) * ED + k0 + sk),
                                       (LBuf*)((char*)&Bs[buf][0] + c * 4096 + tid * 16), 16, 0, 0);
    }
  };

  const int NT = ED / 64;  // 16
  STAGE(0, 0);
  __syncthreads();
  for (int t = 0; t < NT; t++) {
    const int cur = t & 1;
    if (t + 1 < NT) STAGE(t + 1, cur ^ 1);  // flies under compute, drained at barrier
    __builtin_amdgcn_s_setprio(1);
#pragma unroll
    for (int kb = 0; kb < 2; kb++) {
      const int kof = kb * 32 + lg * 8;
      s16x8 a[4], b[4];
#pragma unroll
      for (int i = 0; i < 4; i++)
        a[i] = *(const s16x8*)&As[cur][(wr + i * 16 + ln15) * 64 + kof];
#pragma unroll
      for (int j = 0; j < 4; j++)
        b[j] = *(const s16x8*)&Bs[cur][(wc + j * 16 + ln15) * 64 + kof];
      if (z < 2) {
        // swapped operands: C^T (row = e, col = m) -> packed-hd epilogue
#pragma unroll
        for (int i = 0; i < 4; i++)
#pragma unroll
          for (int j = 0; j < 4; j++)
            acc[i][j] = __builtin_amdgcn_mfma_f32_16x16x32_bf16(b[j], a[i], acc[i][j], 0, 0, 0);
      } else {
#pragma unroll
        for (int i = 0; i < 4; i++)
#pragma unroll
          for (int j = 0; j < 4; j++)
            acc[i][j] = __builtin_amdgcn_mfma_f32_16x16x32_bf16(a[i], b[j], acc[i][j], 0, 0, 0);
      }
    }
    __builtin_amdgcn_s_setprio(0);
    __syncthreads();
  }

  if (z < 2) {
    // C^T: per (i,j): m = m0+wr+i*16+ln15 (fixed/lane), e = n0+wc+j*16+lg*4+r
    const float scale = (z == 0) ? QSC : 1.0f;
    __hip_bfloat16* out = (z == 0) ? Qo : Ko;
#pragma unroll
    for (int i = 0; i < 4; i++) {
      const int m = m0 + wr + i * 16 + ln15;
      const int b = m >> 11, n = m & 2047;
#pragma unroll
      for (int j = 0; j < 4; j++) {
        const int e0 = n0 + wc + j * 16 + lg * 4;   // 4 consecutive e, 4-aligned
        const int h = e0 >> 6, hd = e0 & 63;
        const float4 b4 = *(const float4*)&bias[e0];
        union { s16x4 v; __hip_bfloat16 hh[4]; } pk;
        pk.hh[0] = __float2bfloat16((acc[i][j][0] + b4.x) * scale);
        pk.hh[1] = __float2bfloat16((acc[i][j][1] + b4.y) * scale);
        pk.hh[2] = __float2bfloat16((acc[i][j][2] + b4.z) * scale);
        pk.hh[3] = __float2bfloat16((acc[i][j][3] + b4.w) * scale);
        *(s16x4*)&out[(((size_t)(b * NH + h)) * SEQ + n) * HD + hd] = pk.v;
      }
    }
  } else {
    // V^T scatter: [B*NH][HD][SEQ]; r -> n contiguous -> packed 4-elem stores
#pragma unroll
    for (int j = 0; j < 4; j++) {
      const int e = n0 + wc + j * 16 + ln15;
      const float bvv = bias[e];
      const int h = e >> 6, hd = e & 63;
#pragma unroll
      for (int i = 0; i < 4; i++) {
        const int m = m0 + wr + i * 16 + lg * 4;
        const int b = m >> 11, n = m & 2047;
        union { s16x4 v; __hip_bfloat16 hh[4]; } pk;
#pragma unroll
        for (int r = 0; r < 4; r++) pk.hh[r] = __float2bfloat16(acc[i][j][r] + bvv);
        *(s16x4*)&Vo[(((size_t)(b * NH + h)) * HD + hd) * SEQ + n] = pk.v;
      }
    }
  }
}

// ---------------------------------------------------------------------------
// Output GEMM: 128x128, BK=64, 2-phase dbuf (round-6), fp32 out [M][ED].
// 256 blocks = 1/CU.
// ---------------------------------------------------------------------------
__global__ __launch_bounds__(256) void gemm_out(const __hip_bfloat16* __restrict__ A,
                                                const __hip_bfloat16* __restrict__ W,
                                                const float* __restrict__ bias,
                                                float* __restrict__ out) {
  __shared__ __hip_bfloat16 As[2][128 * 64];
  __shared__ __hip_bfloat16 Bs[2][128 * 64];

  const int lin = blockIdx.y * 8 + blockIdx.x;
  const int work = (lin & 7) * 32 + (lin >> 3);  // 256 blocks, 32/XCD
  const int m0 = (work >> 3) * 128, n0 = (work & 7) * 128;

  const int tid = threadIdx.x;
  const int wave = tid >> 6, lane = tid & 63;
  const int ln15 = lane & 15, lg = lane >> 4;
  const int wr = (wave >> 1) * 64, wc = (wave & 1) * 64;

  f32x4 acc[4][4];
#pragma unroll
  for (int i = 0; i < 4; i++)
#pragma unroll
    for (int j = 0; j < 4; j++) acc[i][j] = (f32x4){0.f, 0.f, 0.f, 0.f};

  const int srow = tid >> 3;
  const int sk = (tid & 7) * 8;

  auto STAGE = [&](int t, int buf) {
    const int k0 = t * 64;
#pragma unroll
    for (int c = 0; c < 4; c++) {
      const int r = c * 32 + srow;
      __builtin_amdgcn_global_load_lds((GBuf*)(A + (size_t)(m0 + r) * ED + k0 + sk),
                                       (LBuf*)((char*)&As[buf][0] + c * 4096 + tid * 16), 16, 0, 0);
      __builtin_amdgcn_global_load_lds((GBuf*)(W + (size_t)(n0 + r) * ED + k0 + sk),
                                       (LBuf*)((char*)&Bs[buf][0] + c * 4096 + tid * 16), 16, 0, 0);
    }
  };

  const int NT = ED / 64;
  STAGE(0, 0);
  __syncthreads();
  for (int t = 0; t < NT; t++) {
    const int cur = t & 1;
    if (t + 1 < NT) STAGE(t + 1, cur ^ 1);
    __builtin_amdgcn_s_setprio(1);
#pragma unroll
    for (int kb = 0; kb < 2; kb++) {
      const int kof = kb * 32 + lg * 8;
      s16x8 a[4], b[4];
#pragma unroll
      for (int i = 0; i < 4; i++)
        a[i] = *(const s16x8*)&As[cur][(wr + i * 16 + ln15) * 64 + kof];
#pragma unroll
      for (int j = 0; j < 4; j++)
        b[j] = *(const s16x8*)&Bs[cur][(wc + j * 16 + ln15) * 64 + kof];
#pragma unroll
      for (int i = 0; i < 4; i++)
#pragma unroll
        for (int j = 0; j < 4; j++)
          acc[i][j] = __builtin_amdgcn_mfma_f32_16x16x32_bf16(a[i], b[j], acc[i][j], 0, 0, 0);
    }
    __builtin_amdgcn_s_setprio(0);
    __syncthreads();
  }

#pragma unroll
  for (int j = 0; j < 4; j++) {
    const int e = n0 + wc + j * 16 + ln15;
    const float bvv = bias[e];
#pragma unroll
    for (int i = 0; i < 4; i++)
#pragma unroll
      for (int r = 0; r < 4; r++) {
        const int m = m0 + wr + i * 16 + lg * 4 + r;
        out[(size_t)m * ED + e] = acc[i][j][r] + bvv;
      }
  }
}

// ---------------------------------------------------------------------------
// Flash attention v5 (measured 67.9 us): split-KV 8-wave, per-parity 2-buffer
// staging, 32x32x16 MFMA, in-register P, defer-max THR=8, final LDS merge.
// ---------------------------------------------------------------------------
__global__ __launch_bounds__(512, 4) void attn_bf16(const __hip_bfloat16* __restrict__ Q,
                                                    const __hip_bfloat16* __restrict__ K,
                                                    const __hip_bfloat16* __restrict__ VT,
                                                    __hip_bfloat16* __restrict__ CTX) {
  __shared__ char ldsraw[65536];
  float* mgacc = (float*)ldsraw;                       // [4][32][66]
  float* mgml = (float*)(ldsraw + 4 * 32 * 66 * 4);    // [4][2][32]

  const int tid = threadIdx.x;
  const int wave = tid >> 6, lane = tid & 63;
  const int l31 = lane & 31, hi = lane >> 5;
  const int rswz = l31 & 7;
  const int par = wave >> 2;   // KV parity group
  const int wq = wave & 3;     // q-group

  const int bid = blockIdx.x;
  const int work = (bid & 7) * 64 + (bid >> 3);
  const int qb = work & 15;
  const int bh = work >> 4;

  const __hip_bfloat16* Qh = Q + (size_t)bh * SEQ * HD;
  const __hip_bfloat16* Kh = K + (size_t)bh * SEQ * HD;
  const __hip_bfloat16* Vh = VT + (size_t)bh * HD * SEQ;

  const int q0 = qb * 128 + wq * 32;

  s16x8 aq[4];
#pragma unroll
  for (int kb = 0; kb < 4; kb++)
    aq[kb] = *(const s16x8*)&Qh[(size_t)(q0 + l31) * HD + kb * 16 + hi * 8];

  f32x16 acc0 = {}, acc1 = {};
  float m_ = -1e30f, l_ = 0.f;

  const int lt = tid & 255;
  auto STAGE = [&](int tile, int buf) {
#pragma unroll
    for (int c = 0; c < 2; c++) {
      const int row = c * 32 + (lt >> 3);
      const int colb = ((lt & 7) * 16) ^ ((row & 7) << 4);
      char* kbase = ldsraw + ((par * 2 + buf) * 2 + 0) * 8192;
      char* vbase = ldsraw + ((par * 2 + buf) * 2 + 1) * 8192;
      __builtin_amdgcn_global_load_lds(
          (GBuf*)((const char*)Kh + ((size_t)(tile * 64 + row) * HD) * 2 + colb),
          (LBuf*)(kbase + c * 4096 + lt * 16), 16, 0, 0);
      __builtin_amdgcn_global_load_lds(
          (GBuf*)((const char*)Vh + ((size_t)row * SEQ + tile * 64) * 2 + colb),
          (LBuf*)(vbase + c * 4096 + lt * 16), 16, 0, 0);
    }
  };

  const int NI = SEQ / 128;  // 16 iterations per parity group
  STAGE(par, 0);
  for (int i = 0; i < NI; i++) {
    const int cur = i & 1;
    __syncthreads();  // drains vmcnt -> buf[cur] staged; prev reads of cur^1 done
    if (i + 1 < NI) STAGE(2 * (i + 1) + par, cur ^ 1);

    const char* Ksb = ldsraw + ((par * 2 + cur) * 2 + 0) * 8192;
    const char* Vtb = ldsraw + ((par * 2 + cur) * 2 + 1) * 8192;

    // ---- S^T = K . Q^T
    f32x16 s0 = {}, s1 = {};
    __builtin_amdgcn_s_setprio(1);
#pragma unroll
    for (int kb = 0; kb < 4; kb++) {
      const int coff = ((kb * 2 + hi) ^ rswz) << 4;
      const s16x8 ak0 = *(const s16x8*)(Ksb + l31 * 128 + coff);
      const s16x8 ak1 = *(const s16x8*)(Ksb + (32 + l31) * 128 + coff);
      s0 = __builtin_amdgcn_mfma_f32_32x32x16_bf16(ak0, aq[kb], s0, 0, 0, 0);
      s1 = __builtin_amdgcn_mfma_f32_32x32x16_bf16(ak1, aq[kb], s1, 0, 0, 0);
    }
    __builtin_amdgcn_s_setprio(0);

    // ---- online softmax (q lane-local)
    float t8[8];
#pragma unroll
    for (int i2 = 0; i2 < 8; i2++)
      t8[i2] = fmaxf(fmaxf(s0[i2], s0[i2 + 8]), fmaxf(s1[i2], s1[i2 + 8]));
    float tm = fmaxf(fmaxf(fmaxf(t8[0], t8[1]), fmaxf(t8[2], t8[3])),
                     fmaxf(fmaxf(t8[4], t8[5]), fmaxf(t8[6], t8[7])));
    tm = fmaxf(tm, __shfl_xor(tm, 32));

    if (!__all(tm - m_ <= 8.0f)) {  // defer-max
      const float mnew = fmaxf(m_, tm);
      const float fs = exp2f(m_ - mnew);
      m_ = mnew;
      l_ *= fs;
#pragma unroll
      for (int r = 0; r < 16; r++) { acc0[r] *= fs; acc1[r] *= fs; }
    }

#pragma unroll
    for (int r = 0; r < 16; r++) {
      s0[r] = exp2f(s0[r] - m_);
      s1[r] = exp2f(s1[r] - m_);
    }
    float sa[8];
#pragma unroll
    for (int i2 = 0; i2 < 8; i2++) sa[i2] = (s0[i2] + s0[i2 + 8]) + (s1[i2] + s1[i2 + 8]);
    float sum = ((sa[0] + sa[1]) + (sa[2] + sa[3])) + ((sa[4] + sa[5]) + (sa[6] + sa[7]));
    sum += __shfl_xor(sum, 32);
    l_ += sum;

    // ---- P fragments in registers
    s16x8 pa[4];
    pa[0] = pack_pfrag(s0[0], s0[1], s0[2], s0[3], s0[4], s0[5], s0[6], s0[7]);
    pa[1] = pack_pfrag(s0[8], s0[9], s0[10], s0[11], s0[12], s0[13], s0[14], s0[15]);
    pa[2] = pack_pfrag(s1[0], s1[1], s1[2], s1[3], s1[4], s1[5], s1[6], s1[7]);
    pa[3] = pack_pfrag(s1[8], s1[9], s1[10], s1[11], s1[12], s1[13], s1[14], s1[15]);

    // ---- O^T += V^T . P^T
    __builtin_amdgcn_s_setprio(1);
#pragma unroll
    for (int kp = 0; kp < 4; kp++) {
      const int coff = ((kp * 2 + hi) ^ rswz) << 4;
      const s16x8 av0 = *(const s16x8*)(Vtb + l31 * 128 + coff);
      const s16x8 av1 = *(const s16x8*)(Vtb + (32 + l31) * 128 + coff);
      acc0 = __builtin_amdgcn_mfma_f32_32x32x16_bf16(av0, pa[kp], acc0, 0, 0, 0);
      acc1 = __builtin_amdgcn_mfma_f32_32x32x16_bf16(av1, pa[kp], acc1, 0, 0, 0);
    }
    __builtin_amdgcn_s_setprio(0);
  }

  // ---- merge the two parity states
  __syncthreads();
  if (wave >= 4) {
    const int w = wave - 4;
    float* ap = &mgacc[(w * 32 + l31) * 66];
#pragma unroll
    for (int g = 0; g < 4; g++)
#pragma unroll
      for (int r = 0; r < 4; r++) {
        ap[8 * g + 4 * hi + r] = acc0[4 * g + r];
        ap[32 + 8 * g + 4 * hi + r] = acc1[4 * g + r];
      }
    if (hi == 0) {
      mgml[(w * 2 + 0) * 32 + l31] = m_;
      mgml[(w * 2 + 1) * 32 + l31] = l_;
    }
  }
  __syncthreads();
  if (wave < 4) {
    const float m1 = mgml[(wave * 2 + 0) * 32 + l31];
    const float l1 = mgml[(wave * 2 + 1) * 32 + l31];
    const float mm = fmaxf(m_, m1);
    const float f0 = exp2f(m_ - mm), f1 = exp2f(m1 - mm);
    const float inv = 1.0f / (l_ * f0 + l1 * f1);
    const float* ap = &mgacc[(wave * 32 + l31) * 66];

    const int b = bh / NH, h = bh % NH;
    const int n = q0 + l31;
    __hip_bfloat16* dst = &CTX[((size_t)(b * SEQ + n)) * ED + h * HD];
#pragma unroll
    for (int g = 0; g < 4; g++) {
      union { s16x4 v; __hip_bfloat16 hh[4]; } p0, p1;
#pragma unroll
      for (int r = 0; r < 4; r++) {
        const float o0 = (acc0[4 * g + r] * f0 + ap[8 * g + 4 * hi + r] * f1) * inv;
        const float o1 = (acc1[4 * g + r] * f0 + ap[32 + 8 * g + 4 * hi + r] * f1) * inv;
        p0.hh[r] = __float2bfloat16(o0);
        p1.hh[r] = __float2bfloat16(o1);
      }
      *(s16x4*)&dst[8 * g + 4 * hi] = p0.v;
      *(s16x4*)&dst[32 + 8 * g + 4 * hi] = p1.v;
    }
  }
}

// ---------------------------------------------------------------------------
extern "C" void kernel_launch(void* const* d_in, const int* in_sizes, int n_in,
                              void* d_out, int out_size, void* d_ws, size_t ws_size,
                              hipStream_t stream) {
  const float* x = (const float*)d_in[0];
  const float* wq = (const float*)d_in[1];
  const float* bq = (const float*)d_in[2];
  const float* wk = (const float*)d_in[3];
  const float* bk = (const float*)d_in[4];
  const float* wv = (const float*)d_in[5];
  const float* bv = (const float*)d_in[6];
  const float* wo = (const float*)d_in[7];
  const float* bo = (const float*)d_in[8];
  float* out = (float*)d_out;

  const int BN = in_sizes[0] / ED;  // 4096

  char* w = (char*)d_ws;
  __hip_bfloat16* xbf = (__hip_bfloat16*)(w);
  __hip_bfloat16* wqb = (__hip_bfloat16*)(w + (8 << 20));
  __hip_bfloat16* wkb = (__hip_bfloat16*)(w + (10 << 20));
  __hip_bfloat16* wvb = (__hip_bfloat16*)(w + (12 << 20));
  __hip_bfloat16* wob = (__hip_bfloat16*)(w + (14 << 20));
  __hip_bfloat16* Qb = (__hip_bfloat16*)(w + (16 << 20));
  __hip_bfloat16* Kb = (__hip_bfloat16*)(w + (24 << 20));
  __hip_bfloat16* VTb = (__hip_bfloat16*)(w + (32 << 20));
  __hip_bfloat16* CTXb = (__hip_bfloat16*)(w + (40 << 20));

  cvt5<<<1024, 256, 0, stream>>>(x, wq, wk, wv, wo, xbf, wqb, wkb, wvb, wob,
                                 BN * ED, ED * ED, ED * ED, ED * ED, ED * ED);

  gemm_qkv<<<dim3(8, 32, 3), dim3(256), 0, stream>>>(
      xbf, wqb, bq, wkb, bk, wvb, bv, Qb, Kb, VTb);

  attn_bf16<<<dim3(512), dim3(512), 0, stream>>>(Qb, Kb, VTb, CTXb);

  gemm_out<<<dim3(8, 32), dim3(256), 0, stream>>>(CTXb, wob, bo, out);
}